// Round 2
// baseline (357.196 us; speedup 1.0000x reference)
//
#include <hip/hip_runtime.h>
#include <hip/hip_bf16.h>

typedef __hip_bfloat16 bf16_t;
typedef __bf16 bf16x8 __attribute__((ext_vector_type(8)));
typedef float f32x4 __attribute__((ext_vector_type(4)));

#define LQ 512
#define LK 4096
#define BATCH 4
#define DMODEL 512
#define NHEAD 8
#define HEADDIM 64
#define DFF 2048
#define LN_EPS 1e-5f

__device__ inline float tofl(float x) { return x; }
__device__ inline float tofl(bf16_t x) { return __bfloat162float(x); }
__device__ inline void stfl(float* p, float v) { *p = v; }
__device__ inline void stfl(bf16_t* p, float v) { *p = __float2bfloat16(v); }

// async global->LDS 16B copy: LDS dest = wave-uniform base + lane*16
__device__ __forceinline__ void gld_lds16(const bf16_t* g, void* lds_base) {
    __builtin_amdgcn_global_load_lds(
        (const __attribute__((address_space(1))) uint32_t*)g,
        (__attribute__((address_space(3))) uint32_t*)lds_base, 16, 0, 0);
}

// ---------- prep: all weight conversions + attn_out zero-fill ----------
__global__ void prep_kernel(const float* __restrict__ s0, const float* __restrict__ s1,
                            const float* __restrict__ s2, const float* __restrict__ s3,
                            const float* __restrict__ s4, const float* __restrict__ s5,
                            bf16_t* __restrict__ wqkvo, bf16_t* __restrict__ w1bf,
                            bf16_t* __restrict__ w2bf, float* __restrict__ zbuf) {
    int bid = blockIdx.x;
    int tid = threadIdx.x;
    if (bid < 3072) {
        int t = bid * 256 + tid;
        int which = t >> 16;            // 0..11, 262144 elements each
        int idx = (t & 65535) * 4;
        const float* s; bf16_t* d;
        if (which < 4) {
            s = (which == 0 ? s0 : which == 1 ? s1 : which == 2 ? s2 : s3) ;
            d = wqkvo + (size_t)which * 262144;
        } else if (which < 8) {
            s = s4 + (size_t)(which - 4) * 262144;
            d = w1bf + (size_t)(which - 4) * 262144;
        } else {
            s = s5 + (size_t)(which - 8) * 262144;
            d = w2bf + (size_t)(which - 8) * 262144;
        }
        float4 v = *(const float4*)(s + idx);
        d[idx + 0] = __float2bfloat16(v.x);
        d[idx + 1] = __float2bfloat16(v.y);
        d[idx + 2] = __float2bfloat16(v.z);
        d[idx + 3] = __float2bfloat16(v.w);
    } else {
        size_t i = ((size_t)(bid - 3072) * 256 + tid) * 4;
        float4 z = {0.f, 0.f, 0.f, 0.f};
        *(float4*)(zbuf + i) = z;
    }
}

// ---------- LayerNorm (generic, templated) ----------
template <typename TOUT, bool DUAL>
__global__ void ln_kernel(const float* __restrict__ in, const float* __restrict__ w,
                          const float* __restrict__ b, TOUT* __restrict__ out1,
                          float* __restrict__ out2) {
    __shared__ float red[256];
    const int row = blockIdx.x;
    const int tid = threadIdx.x;
    const float* x = in + (size_t)row * DMODEL;
    float v0 = x[tid];
    float v1 = x[tid + 256];

    red[tid] = v0 + v1;
    __syncthreads();
    for (int s = 128; s > 0; s >>= 1) { if (tid < s) red[tid] += red[tid + s]; __syncthreads(); }
    float mu = red[0] * (1.0f / DMODEL);
    __syncthreads();

    float d0 = v0 - mu, d1 = v1 - mu;
    red[tid] = d0 * d0 + d1 * d1;
    __syncthreads();
    for (int s = 128; s > 0; s >>= 1) { if (tid < s) red[tid] += red[tid + s]; __syncthreads(); }
    float inv = rsqrtf(red[0] * (1.0f / DMODEL) + LN_EPS);

    float r0 = d0 * inv * w[tid] + b[tid];
    float r1 = d1 * inv * w[tid + 256] + b[tid + 256];
    TOUT* o = out1 + (size_t)row * DMODEL;
    stfl(&o[tid], r0);
    stfl(&o[tid + 256], r1);
    if (DUAL) {
        float* o2 = out2 + (size_t)row * DMODEL;
        o2[tid] = r0;
        o2[tid + 256] = r1;
    }
}

// ---------- fused LN1 + LN2 ----------
__global__ void ln12_kernel(const float* __restrict__ tgt, const float* __restrict__ memory,
                            const float* __restrict__ w1, const float* __restrict__ b1,
                            const float* __restrict__ w2, const float* __restrict__ b2,
                            bf16_t* __restrict__ t_bf, float* __restrict__ t_f32,
                            bf16_t* __restrict__ m_buf) {
    __shared__ float red[256];
    const int row = blockIdx.x;
    const int tid = threadIdx.x;
    const float* in; const float* w; const float* b;
    bf16_t* o1; float* o2; bool dual;
    if (row < 2048) {
        in = tgt + (size_t)row * DMODEL; w = w1; b = b1;
        o1 = t_bf + (size_t)row * DMODEL; o2 = t_f32 + (size_t)row * DMODEL; dual = true;
    } else {
        int r2 = row - 2048;
        in = memory + (size_t)r2 * DMODEL; w = w2; b = b2;
        o1 = m_buf + (size_t)r2 * DMODEL; o2 = nullptr; dual = false;
    }
    float v0 = in[tid];
    float v1 = in[tid + 256];
    red[tid] = v0 + v1;
    __syncthreads();
    for (int s = 128; s > 0; s >>= 1) { if (tid < s) red[tid] += red[tid + s]; __syncthreads(); }
    float mu = red[0] * (1.0f / DMODEL);
    __syncthreads();
    float d0 = v0 - mu, d1 = v1 - mu;
    red[tid] = d0 * d0 + d1 * d1;
    __syncthreads();
    for (int s = 128; s > 0; s >>= 1) { if (tid < s) red[tid] += red[tid + s]; __syncthreads(); }
    float inv = rsqrtf(red[0] * (1.0f / DMODEL) + LN_EPS);
    float r0 = d0 * inv * w[tid] + b[tid];
    float r1 = d1 * inv * w[tid + 256] + b[tid + 256];
    o1[tid] = __float2bfloat16(r0);
    o1[tid + 256] = __float2bfloat16(r1);
    if (dual) {
        o2[tid] = r0;
        o2[tid + 256] = r1;
    }
}

// ---------- MFMA GEMM, coalesced+swizzled global_load_lds staging ----------
template <int TN, typename TC, bool RELU, bool RESID>
__global__ __launch_bounds__(256) void gemm_mfma(
        const bf16_t* __restrict__ A, const bf16_t* __restrict__ B,
        const float* __restrict__ bias, const float* __restrict__ resid,
        TC* __restrict__ C, int M, int N, int K) {
    __shared__ uint4 As4[1024];          // 128 rows x 8 chunks
    __shared__ uint4 Bs4[TN * 8];        // TN rows x 8 chunks

    const int tid = threadIdx.x;
    const int lane = tid & 63;
    const int wave = tid >> 6;
    const int row16 = lane & 15;
    const int quad = lane >> 4;
    const int n0 = blockIdx.x * TN;
    const int m0 = blockIdx.y * 128;

    constexpr int MI = (TN == 128) ? 4 : 2;           // 16-row frags per wave in M
    const int wy = (TN == 128) ? (wave >> 1) : wave;
    const int wx = (TN == 128) ? (wave & 1) : 0;
    const int m_base = wy * ((TN == 128) ? 64 : 32);
    const int n_base = wx * 64;

    const int rr = lane >> 3;            // 0..7 (row within issue)
    const int kc = (lane & 7) ^ rr;      // swizzled global k-chunk
    const int kx = row16 & 7;            // frag-read deswizzle key

    const bf16_t* AsE = (const bf16_t*)As4;
    const bf16_t* BsE = (const bf16_t*)Bs4;

    f32x4 acc[MI][4] = {};

    for (int k0 = 0; k0 < K; k0 += 64) {
        // stage A: 16 issues x 8 rows
#pragma unroll
        for (int it = 0; it < 4; it++) {
            int issue = it * 4 + wave;
            int r = issue * 8 + rr;
            gld_lds16(A + (size_t)(m0 + r) * K + k0 + kc * 8, &As4[issue * 64]);
        }
        // stage B: TN/8 issues
#pragma unroll
        for (int it = 0; it < TN / 32; it++) {
            int issue = it * 4 + wave;
            int r = issue * 8 + rr;
            gld_lds16(B + (size_t)(n0 + r) * K + k0 + kc * 8, &Bs4[issue * 64]);
        }
        __syncthreads();
#pragma unroll
        for (int s = 0; s < 2; s++) {
            const int kq = s * 4 + quad;
            const int kcs = (kq ^ kx) * 8;
            bf16x8 af[MI], bfr[4];
#pragma unroll
            for (int i = 0; i < MI; i++)
                af[i] = *(const bf16x8*)&AsE[(m_base + i * 16 + row16) * 64 + kcs];
#pragma unroll
            for (int j = 0; j < 4; j++)
                bfr[j] = *(const bf16x8*)&BsE[(n_base + j * 16 + row16) * 64 + kcs];
#pragma unroll
            for (int i = 0; i < MI; i++)
#pragma unroll
                for (int j = 0; j < 4; j++)
                    acc[i][j] = __builtin_amdgcn_mfma_f32_16x16x32_bf16(af[i], bfr[j], acc[i][j], 0, 0, 0);
        }
        __syncthreads();
    }

#pragma unroll
    for (int i = 0; i < MI; i++) {
#pragma unroll
        for (int j = 0; j < 4; j++) {
            int col = n0 + n_base + j * 16 + row16;
            float bsv = bias[col];
#pragma unroll
            for (int r = 0; r < 4; r++) {
                int row = m0 + m_base + i * 16 + quad * 4 + r;
                float val = acc[i][j][r] + bsv;
                if (RESID) val += resid[(size_t)row * N + col];
                if (RELU) val = fmaxf(val, 0.0f);
                stfl(&C[(size_t)row * N + col], val);
            }
        }
    }
}

// ---------- transpose: in[(key*4+b)*512 + c] -> out[(b*512+c)*4096 + key] ----------
__global__ __launch_bounds__(256) void transpose_kv(const bf16_t* __restrict__ kb,
                                                    bf16_t* __restrict__ kT) {
    __shared__ bf16_t tile[64][80];
    const int kt = blockIdx.x * 64;
    const int ct = blockIdx.y * 64;
    const int b  = blockIdx.z;
    const int t = threadIdx.x;
    {
        int kl = t >> 2, cl = (t & 3) * 16;
        const bf16_t* src = kb + ((size_t)(kt + kl) * 4 + b) * 512 + ct + cl;
        *(uint4*)&tile[kl][cl]     = *(const uint4*)src;
        *(uint4*)&tile[kl][cl + 8] = *(const uint4*)(src + 8);
    }
    __syncthreads();
    {
        int cl2 = t >> 2, ks = (t & 3) * 16;
        __attribute__((aligned(16))) bf16_t vals[16];
#pragma unroll
        for (int j = 0; j < 16; j++) vals[j] = tile[ks + j][cl2];
        bf16_t* dst = kT + ((size_t)b * 512 + ct + cl2) * 4096 + kt + ks;
        *(uint4*)dst       = *(const uint4*)&vals[0];
        *(uint4*)(dst + 8) = *(const uint4*)&vals[8];
    }
}

// ---------- MFMA flash attention v3 ----------
// R1 post-mortem: occupancy 2x -> dur -2.7%. Not TLP-starved; per-wave serial
// load-latency chain dominates. v3: (a) 8-deep register prefetch in QK,
// (b) 4-deep in PV, (c) barrier-free QK->PV transition (PV reads only own Ps),
// (d) attn-mean atomics moved AFTER PV so they don't sit ahead of PV loads in
// the vmcnt FIFO. VGPR 52 -> ~120 (free: occupancy is LDS-limited at 2 blk/CU).
__global__ __launch_bounds__(512, 4) void attn_mfma(
        const bf16_t* __restrict__ qb,   // [2048,512] rows (q*4+b)
        const bf16_t* __restrict__ kb,   // [16384,512] rows (key*4+b)
        const bf16_t* __restrict__ vT,   // [4][512][4096]
        bf16_t* __restrict__ ctx,        // [2048,512]
        float* __restrict__ attn_out) {  // [4][512][4096], pre-zeroed
    const int d = blockIdx.x;
    const int g = d & 7;
    const int b = g >> 1;
    const int qhalf = g & 1;
    const int i_in = d >> 3;
    const int hg = i_in & 1;
    const int qt = qhalf * 32 + (i_in >> 1);
    const int q0 = qt * 8;
    const int tid = threadIdx.x;
    const int lane = tid & 63;
    const int w8 = tid >> 6;         // 0..7
    const int hw = w8 & 3;           // head within group
    const int half = w8 >> 2;        // key-window half (0/1)
    const int h = hg * 4 + hw;
    const int hoffg = h * HEADDIM;
    const int hl = hw * HEADDIM;
    const int row16 = lane & 15;
    const int quad = lane >> 4;

    __align__(16) __shared__ bf16_t Qs[8][264];
    __align__(16) __shared__ bf16_t Zrow[904];
    __align__(16) __shared__ bf16_t Ps[4][8][904];
    __shared__ float Ls2[2][4][8];   // [half][head][qrow] partial denominators

    int us; { int s = q0 * 8, e = s + 827; if (e > 4095) s = 3268; us = s; }
    int sq[4], eq[4];
#pragma unroll
    for (int r = 0; r < 4; r++) {
        int ql = quad * 4 + r;
        if (ql < 8) {
            int s = (q0 + ql) * 8, e = s + 827;
            if (e > 4095) { s = 3268; e = 4096; }
            sq[r] = s; eq[r] = e;
        } else { sq[r] = 0; eq[r] = 0; }
    }

    if (tid < 256) {
        int r = tid >> 5, coff = (tid & 31) * 8;
        *(uint4*)&Qs[r][coff] =
            *(const uint4*)(qb + ((size_t)(q0 + r) * 4 + b) * 512 + hg * 256 + coff);
        if (tid < 113) { uint4 z = {0, 0, 0, 0}; *(uint4*)&Zrow[tid * 8] = z; }
    }
    __syncthreads();

    const bf16_t* q0p = (row16 < 8) ? &Qs[row16][hl + quad * 8] : &Zrow[0];
    const bf16_t* q1p = (row16 < 8) ? &Qs[row16][hl + 32 + quad * 8] : &Zrow[8];
    const bf16x8 aq0 = *(const bf16x8*)q0p;
    const bf16x8 aq1 = *(const bf16x8*)q1p;

    // ---- QK phase: 28 iterations, 8-deep register prefetch ----
    const int it0 = half * 28;
    const bf16_t* kb_base = kb + (size_t)b * 512 + hoffg + quad * 8;
    auto kaddr = [&](int it) -> const bf16_t* {
        int key = us + it * 16 + row16;
        int key_eff = key > 4095 ? 4095 : key;
        return kb_base + (size_t)key_eff * 2048;
    };
    bf16x8 kbuf0[8], kbuf1[8];
#pragma unroll
    for (int j = 0; j < 8; ++j) {
        const bf16_t* p = kaddr(it0 + j);
        kbuf0[j] = *(const bf16x8*)p;
        kbuf1[j] = *(const bf16x8*)(p + 32);
    }
    float l[4] = {0.f, 0.f, 0.f, 0.f};
#pragma unroll
    for (int j = 0; j < 28; ++j) {
        const int it = it0 + j;
        f32x4 acc = {};
        acc = __builtin_amdgcn_mfma_f32_16x16x32_bf16(aq0, kbuf0[j & 7], acc, 0, 0, 0);
        acc = __builtin_amdgcn_mfma_f32_16x16x32_bf16(aq1, kbuf1[j & 7], acc, 0, 0, 0);
        if (j + 8 < 28) {
            const bf16_t* p = kaddr(it + 8);
            kbuf0[j & 7] = *(const bf16x8*)p;
            kbuf1[j & 7] = *(const bf16x8*)(p + 32);
        }
        const int key = us + it * 16 + row16;
#pragma unroll
        for (int r = 0; r < 4; r++) {
            int ql = quad * 4 + r;
            bool valid = (key >= sq[r]) && (key < eq[r]);
            float p = valid ? __expf(0.125f * acc[r]) : 0.0f;
            l[r] += p;
            if (ql < 8) Ps[hw][ql][it * 16 + row16] = __float2bfloat16(p);
        }
    }
#pragma unroll
    for (int off = 1; off < 16; off <<= 1) {
#pragma unroll
        for (int r = 0; r < 4; r++) l[r] += __shfl_xor(l[r], off, 64);
    }
    if (row16 == 0) {
#pragma unroll
        for (int r = 0; r < 4; r++) {
            int ql = quad * 4 + r;
            if (ql < 8) Ls2[half][hw][ql] = l[r];
        }
    }

    // ---- PV phase: no barrier needed (reads only this wave's own Ps cols) ----
    const int pv0 = half * 14;
    auto vaddr = [&](int it, int nt) -> const bf16_t* {
        return vT + ((size_t)b * 512 + hoffg + nt * 16 + row16) * 4096
               + us + it * 32 + quad * 8;
    };
    bf16x8 vbuf[4][4];
#pragma unroll
    for (int j = 0; j < 4; ++j)
#pragma unroll
        for (int nt = 0; nt < 4; ++nt) vbuf[j][nt] = *(const bf16x8*)vaddr(pv0 + j, nt);

    f32x4 o[4] = {};
#pragma unroll
    for (int j = 0; j < 14; ++j) {
        const int it = pv0 + j;
        const bf16_t* ap_src = (row16 < 8) ? &Ps[hw][row16][it * 32 + quad * 8]
                                           : &Zrow[0];
        bf16x8 ap = *(const bf16x8*)ap_src;
#pragma unroll
        for (int nt = 0; nt < 4; ++nt)
            o[nt] = __builtin_amdgcn_mfma_f32_16x16x32_bf16(ap, vbuf[j & 3][nt], o[nt], 0, 0, 0);
        if (j + 4 < 14) {
#pragma unroll
            for (int nt = 0; nt < 4; ++nt) vbuf[j & 3][nt] = *(const bf16x8*)vaddr(it + 4, nt);
        }
    }

    __syncthreads();   // B1: all waves' Ps + Ls2 final

    // ---- attn_out head-mean (after PV so atomics don't stall PV's loads) ----
    {
        int qq = w8;
        float ls0 = 0.125f / (Ls2[0][0][qq] + Ls2[1][0][qq]);
        float ls1 = 0.125f / (Ls2[0][1][qq] + Ls2[1][1][qq]);
        float ls2 = 0.125f / (Ls2[0][2][qq] + Ls2[1][2][qq]);
        float ls3 = 0.125f / (Ls2[0][3][qq] + Ls2[1][3][qq]);
        float* base = attn_out + ((size_t)b * LQ + q0 + qq) * LK + us;
        const int cmax = LK - us;
        for (int col = lane; col < 896; col += 64) {
            if (col < cmax) {
                float s = ls0 * tofl(Ps[0][qq][col]) + ls1 * tofl(Ps[1][qq][col]) +
                          ls2 * tofl(Ps[2][qq][col]) + ls3 * tofl(Ps[3][qq][col]);
                atomicAdd(base + col, s);
            }
        }
    }

    float linv[4];
#pragma unroll
    for (int r = 0; r < 4; r++) {
        int ql = quad * 4 + r;
        linv[r] = (ql < 8) ? 1.0f / (Ls2[0][hw][ql] + Ls2[1][hw][ql]) : 0.0f;
    }

    // ---- combine the two halves' partial o through the (now dead) Ps region ----
    __syncthreads();   // B2: all Ps reads (mean loop) done
    float* Osum = (float*)Ps;        // [4 heads][8 rows] x 65-stride x 64 dims
    if (half == 1) {
#pragma unroll
        for (int nt = 0; nt < 4; nt++) {
#pragma unroll
            for (int r = 0; r < 4; r++) {
                int ql = quad * 4 + r;
                if (ql < 8) Osum[(hw * 8 + ql) * 65 + nt * 16 + row16] = o[nt][r];
            }
        }
    }
    __syncthreads();   // B3
    if (half == 0) {
#pragma unroll
        for (int nt = 0; nt < 4; nt++) {
#pragma unroll
            for (int r = 0; r < 4; r++) {
                int ql = quad * 4 + r;
                if (ql < 8) {
                    float tot = o[nt][r] + Osum[(hw * 8 + ql) * 65 + nt * 16 + row16];
                    ctx[((size_t)(q0 + ql) * 4 + b) * 512 + hoffg + nt * 16 + row16] =
                        __float2bfloat16(tot * linv[r]);
                }
            }
        }
    }
}

extern "C" void kernel_launch(void* const* d_in, const int* in_sizes, int n_in,
                              void* d_out, int out_size, void* d_ws, size_t ws_size,
                              hipStream_t stream) {
    const float* tgt    = (const float*)d_in[0];
    const float* memory = (const float*)d_in[1];
    const float* Wq = (const float*)d_in[2];
    const float* bq = (const float*)d_in[3];
    const float* Wk = (const float*)d_in[4];
    const float* bk = (const float*)d_in[5];
    const float* Wv = (const float*)d_in[6];
    const float* bv = (const float*)d_in[7];
    const float* Wo = (const float*)d_in[8];
    const float* bo = (const float*)d_in[9];
    const float* W1 = (const float*)d_in[10];
    const float* b1 = (const float*)d_in[11];
    const float* W2 = (const float*)d_in[12];
    const float* b2 = (const float*)d_in[13];
    const float* ln1w = (const float*)d_in[14];
    const float* ln1b = (const float*)d_in[15];
    const float* ln2w = (const float*)d_in[16];
    const float* ln2b = (const float*)d_in[17];
    const float* ln3w = (const float*)d_in[18];
    const float* ln3b = (const float*)d_in[19];
    const float* ln4w = (const float*)d_in[20];
    const float* ln4b = (const float*)d_in[21];

    const size_t M1 = (size_t)LQ * BATCH;      // 2048
    const size_t M2 = (size_t)LK * BATCH;      // 16384
    const size_t SZ1 = M1 * DMODEL;

    // ---- workspace map (64 MiB, lifetime-aliased) ----
    char* wsb = (char*)d_ws;
    const size_t MB = 1 << 20;
    bf16_t* m_buf   = (bf16_t*)(wsb + 0 * MB);
    bf16_t* vT_buf  = (bf16_t*)(wsb + 0 * MB);
    bf16_t* h_buf   = (bf16_t*)(wsb + 0 * MB);
    float*  xln_f   = (float*)(wsb + 8 * MB);
    float*  x2_buf  = (float*)(wsb + 12 * MB);
    bf16_t* k_buf   = (bf16_t*)(wsb + 16 * MB);
    bf16_t* v_buf   = (bf16_t*)(wsb + 32 * MB);
    float*  xres    = (float*)(wsb + 32 * MB);   // after transpose (v dead)
    bf16_t* t_bf    = (bf16_t*)(wsb + 48 * MB);
    bf16_t* xln_bf  = (bf16_t*)(wsb + 48 * MB);
    float*  t_f32   = (float*)(wsb + 50 * MB);
    bf16_t* q_bf    = (bf16_t*)(wsb + 54 * MB);
    bf16_t* W2_bf   = (bf16_t*)(wsb + 56 * MB);
    bf16_t* ctx_buf = (bf16_t*)(wsb + 58 * MB);
    bf16_t* wqkvo   = (bf16_t*)(wsb + 60 * MB);
    bf16_t* W1_bf   = (bf16_t*)(wsb + 62 * MB);

    bf16_t* Wq_bf = wqkvo;
    bf16_t* Wk_bf = wqkvo + 262144;
    bf16_t* Wv_bf = wqkvo + 2 * 262144;
    bf16_t* Wo_bf = wqkvo + 3 * 262144;

    float* out_x    = (float*)d_out;
    float* out_attn = out_x + SZ1;

    // 1. all conversions + attn_out zero
    prep_kernel<<<dim3(11264), dim3(256), 0, stream>>>(
        Wq, Wk, Wv, Wo, W1, W2, wqkvo, W1_bf, W2_bf, out_attn);

    // 2. LN1 (dual) + LN2 fused
    ln12_kernel<<<dim3(M1 + M2), dim3(256), 0, stream>>>(
        tgt, memory, ln1w, ln1b, ln2w, ln2b, t_bf, t_f32, m_buf);

    // 3-5. projections
    gemm_mfma<64, bf16_t, false, false><<<dim3(8, 16), dim3(256), 0, stream>>>(
        t_bf, Wq_bf, bq, nullptr, q_bf, M1, DMODEL, DMODEL);
    gemm_mfma<128, bf16_t, false, false><<<dim3(4, 128), dim3(256), 0, stream>>>(
        m_buf, Wk_bf, bk, nullptr, k_buf, M2, DMODEL, DMODEL);
    gemm_mfma<128, bf16_t, false, false><<<dim3(4, 128), dim3(256), 0, stream>>>(
        m_buf, Wv_bf, bv, nullptr, v_buf, M2, DMODEL, DMODEL);

    // 6. V transpose to [b][d][key] (m_buf dead -> vT region)
    transpose_kv<<<dim3(64, 8, 4), dim3(256), 0, stream>>>(v_buf, vT_buf);

    // 7. attention (8 waves: 4 heads x 2 key-halves, register-prefetch pipelines)
    attn_mfma<<<dim3(512), dim3(512), 0, stream>>>(q_bf, k_buf, vT_buf, ctx_buf, out_attn);

    // 8. out proj + residual(t) -> xres (v_buf region, dead)
    gemm_mfma<64, float, false, true><<<dim3(8, 16), dim3(256), 0, stream>>>(
        ctx_buf, Wo_bf, bo, t_f32, xres, M1, DMODEL, DMODEL);

    // 9. LN3 (dual)
    ln_kernel<bf16_t, true><<<dim3(M1), dim3(256), 0, stream>>>(xres, ln3w, ln3b, xln_bf, xln_f);

    // 10. FF1 (relu)
    gemm_mfma<128, bf16_t, true, false><<<dim3(16, 16), dim3(256), 0, stream>>>(
        xln_bf, W1_bf, b1, nullptr, h_buf, M1, DFF, DMODEL);

    // 11. FF2 + residual(xln)
    gemm_mfma<64, float, false, true><<<dim3(8, 16), dim3(256), 0, stream>>>(
        h_buf, W2_bf, b2, xln_f, x2_buf, M1, DMODEL, DFF);

    // 12. LN4 -> fp32 out
    ln_kernel<float, false><<<dim3(M1), dim3(256), 0, stream>>>(x2_buf, ln4w, ln4b, out_x, nullptr);
}

// Round 3
// 325.124 us; speedup vs baseline: 1.0986x; 1.0986x over previous
//
#include <hip/hip_runtime.h>
#include <hip/hip_bf16.h>

typedef __hip_bfloat16 bf16_t;
typedef __bf16 bf16x8 __attribute__((ext_vector_type(8)));
typedef float f32x4 __attribute__((ext_vector_type(4)));

#define LQ 512
#define LK 4096
#define BATCH 4
#define DMODEL 512
#define NHEAD 8
#define HEADDIM 64
#define DFF 2048
#define LN_EPS 1e-5f

// padded strides (break 4KB/8KB L2 channel aliasing: rotate 32B per row mod 4KB)
#define KSTR 2064   // elements per key in k_buf: [4096][4*512 + 16]
#define VSTR 4112   // elements per (b,c) row in vT: [4][512][4096 + 16]

__device__ inline float tofl(float x) { return x; }
__device__ inline float tofl(bf16_t x) { return __bfloat162float(x); }
__device__ inline void stfl(float* p, float v) { *p = v; }
__device__ inline void stfl(bf16_t* p, float v) { *p = __float2bfloat16(v); }

// async global->LDS 16B copy: LDS dest = wave-uniform base + lane*16
__device__ __forceinline__ void gld_lds16(const bf16_t* g, void* lds_base) {
    __builtin_amdgcn_global_load_lds(
        (const __attribute__((address_space(1))) uint32_t*)g,
        (__attribute__((address_space(3))) uint32_t*)lds_base, 16, 0, 0);
}

// ---------- prep: Wq/Wk/Wv/Wo + W1 conversions + attn_out zero-fill ----------
__global__ void prep_kernel(const float* __restrict__ s0, const float* __restrict__ s1,
                            const float* __restrict__ s2, const float* __restrict__ s3,
                            const float* __restrict__ s4,
                            bf16_t* __restrict__ wqkvo, bf16_t* __restrict__ w1bf,
                            float* __restrict__ zbuf) {
    int bid = blockIdx.x;
    int tid = threadIdx.x;
    if (bid < 2048) {
        int t = bid * 256 + tid;
        int which = t >> 16;            // 0..7, 262144 elements each
        int idx = (t & 65535) * 4;
        const float* s; bf16_t* d;
        if (which < 4) {
            s = (which == 0 ? s0 : which == 1 ? s1 : which == 2 ? s2 : s3);
            d = wqkvo + (size_t)which * 262144;
        } else {
            s = s4 + (size_t)(which - 4) * 262144;
            d = w1bf + (size_t)(which - 4) * 262144;
        }
        float4 v = *(const float4*)(s + idx);
        d[idx + 0] = __float2bfloat16(v.x);
        d[idx + 1] = __float2bfloat16(v.y);
        d[idx + 2] = __float2bfloat16(v.z);
        d[idx + 3] = __float2bfloat16(v.w);
    } else {
        size_t i = ((size_t)(bid - 2048) * 256 + tid) * 4;
        float4 z = {0.f, 0.f, 0.f, 0.f};
        *(float4*)(zbuf + i) = z;
    }
}

// ---------- W2 conversion (runs after transpose; lands in dead v_buf region) ----------
__global__ void conv_w2(const float* __restrict__ s, bf16_t* __restrict__ d) {
    int i = (blockIdx.x * 256 + threadIdx.x) * 4;
    float4 v = *(const float4*)(s + i);
    d[i + 0] = __float2bfloat16(v.x);
    d[i + 1] = __float2bfloat16(v.y);
    d[i + 2] = __float2bfloat16(v.z);
    d[i + 3] = __float2bfloat16(v.w);
}

// ---------- LayerNorm (generic, templated) ----------
template <typename TOUT, bool DUAL>
__global__ void ln_kernel(const float* __restrict__ in, const float* __restrict__ w,
                          const float* __restrict__ b, TOUT* __restrict__ out1,
                          float* __restrict__ out2) {
    __shared__ float red[256];
    const int row = blockIdx.x;
    const int tid = threadIdx.x;
    const float* x = in + (size_t)row * DMODEL;
    float v0 = x[tid];
    float v1 = x[tid + 256];

    red[tid] = v0 + v1;
    __syncthreads();
    for (int s = 128; s > 0; s >>= 1) { if (tid < s) red[tid] += red[tid + s]; __syncthreads(); }
    float mu = red[0] * (1.0f / DMODEL);
    __syncthreads();

    float d0 = v0 - mu, d1 = v1 - mu;
    red[tid] = d0 * d0 + d1 * d1;
    __syncthreads();
    for (int s = 128; s > 0; s >>= 1) { if (tid < s) red[tid] += red[tid + s]; __syncthreads(); }
    float inv = rsqrtf(red[0] * (1.0f / DMODEL) + LN_EPS);

    float r0 = d0 * inv * w[tid] + b[tid];
    float r1 = d1 * inv * w[tid + 256] + b[tid + 256];
    TOUT* o = out1 + (size_t)row * DMODEL;
    stfl(&o[tid], r0);
    stfl(&o[tid + 256], r1);
    if (DUAL) {
        float* o2 = out2 + (size_t)row * DMODEL;
        o2[tid] = r0;
        o2[tid + 256] = r1;
    }
}

// ---------- fused LN1 + LN2 ----------
__global__ void ln12_kernel(const float* __restrict__ tgt, const float* __restrict__ memory,
                            const float* __restrict__ w1, const float* __restrict__ b1,
                            const float* __restrict__ w2, const float* __restrict__ b2,
                            bf16_t* __restrict__ t_bf, float* __restrict__ t_f32,
                            bf16_t* __restrict__ m_buf) {
    __shared__ float red[256];
    const int row = blockIdx.x;
    const int tid = threadIdx.x;
    const float* in; const float* w; const float* b;
    bf16_t* o1; float* o2; bool dual;
    if (row < 2048) {
        in = tgt + (size_t)row * DMODEL; w = w1; b = b1;
        o1 = t_bf + (size_t)row * DMODEL; o2 = t_f32 + (size_t)row * DMODEL; dual = true;
    } else {
        int r2 = row - 2048;
        in = memory + (size_t)r2 * DMODEL; w = w2; b = b2;
        o1 = m_buf + (size_t)r2 * DMODEL; o2 = nullptr; dual = false;
    }
    float v0 = in[tid];
    float v1 = in[tid + 256];
    red[tid] = v0 + v1;
    __syncthreads();
    for (int s = 128; s > 0; s >>= 1) { if (tid < s) red[tid] += red[tid + s]; __syncthreads(); }
    float mu = red[0] * (1.0f / DMODEL);
    __syncthreads();
    float d0 = v0 - mu, d1 = v1 - mu;
    red[tid] = d0 * d0 + d1 * d1;
    __syncthreads();
    for (int s = 128; s > 0; s >>= 1) { if (tid < s) red[tid] += red[tid + s]; __syncthreads(); }
    float inv = rsqrtf(red[0] * (1.0f / DMODEL) + LN_EPS);
    float r0 = d0 * inv * w[tid] + b[tid];
    float r1 = d1 * inv * w[tid + 256] + b[tid + 256];
    o1[tid] = __float2bfloat16(r0);
    o1[tid + 256] = __float2bfloat16(r1);
    if (dual) {
        o2[tid] = r0;
        o2[tid + 256] = r1;
    }
}

// ---------- MFMA GEMM, coalesced+swizzled global_load_lds staging ----------
// KREMAP: C-write goes to the key-padded k_buf layout (row=key*4+b ->
//   addr = key*KSTR + b*512 + col) to break 4KB channel aliasing in attn.
template <int TN, typename TC, bool RELU, bool RESID, bool KREMAP = false>
__global__ __launch_bounds__(256) void gemm_mfma(
        const bf16_t* __restrict__ A, const bf16_t* __restrict__ B,
        const float* __restrict__ bias, const float* __restrict__ resid,
        TC* __restrict__ C, int M, int N, int K) {
    __shared__ uint4 As4[1024];          // 128 rows x 8 chunks
    __shared__ uint4 Bs4[TN * 8];        // TN rows x 8 chunks

    const int tid = threadIdx.x;
    const int lane = tid & 63;
    const int wave = tid >> 6;
    const int row16 = lane & 15;
    const int quad = lane >> 4;
    const int n0 = blockIdx.x * TN;
    const int m0 = blockIdx.y * 128;

    constexpr int MI = (TN == 128) ? 4 : 2;           // 16-row frags per wave in M
    const int wy = (TN == 128) ? (wave >> 1) : wave;
    const int wx = (TN == 128) ? (wave & 1) : 0;
    const int m_base = wy * ((TN == 128) ? 64 : 32);
    const int n_base = wx * 64;

    const int rr = lane >> 3;            // 0..7 (row within issue)
    const int kc = (lane & 7) ^ rr;      // swizzled global k-chunk
    const int kx = row16 & 7;            // frag-read deswizzle key

    const bf16_t* AsE = (const bf16_t*)As4;
    const bf16_t* BsE = (const bf16_t*)Bs4;

    f32x4 acc[MI][4] = {};

    for (int k0 = 0; k0 < K; k0 += 64) {
        // stage A: 16 issues x 8 rows
#pragma unroll
        for (int it = 0; it < 4; it++) {
            int issue = it * 4 + wave;
            int r = issue * 8 + rr;
            gld_lds16(A + (size_t)(m0 + r) * K + k0 + kc * 8, &As4[issue * 64]);
        }
        // stage B: TN/8 issues
#pragma unroll
        for (int it = 0; it < TN / 32; it++) {
            int issue = it * 4 + wave;
            int r = issue * 8 + rr;
            gld_lds16(B + (size_t)(n0 + r) * K + k0 + kc * 8, &Bs4[issue * 64]);
        }
        __syncthreads();
#pragma unroll
        for (int s = 0; s < 2; s++) {
            const int kq = s * 4 + quad;
            const int kcs = (kq ^ kx) * 8;
            bf16x8 af[MI], bfr[4];
#pragma unroll
            for (int i = 0; i < MI; i++)
                af[i] = *(const bf16x8*)&AsE[(m_base + i * 16 + row16) * 64 + kcs];
#pragma unroll
            for (int j = 0; j < 4; j++)
                bfr[j] = *(const bf16x8*)&BsE[(n_base + j * 16 + row16) * 64 + kcs];
#pragma unroll
            for (int i = 0; i < MI; i++)
#pragma unroll
                for (int j = 0; j < 4; j++)
                    acc[i][j] = __builtin_amdgcn_mfma_f32_16x16x32_bf16(af[i], bfr[j], acc[i][j], 0, 0, 0);
        }
        __syncthreads();
    }

#pragma unroll
    for (int i = 0; i < MI; i++) {
#pragma unroll
        for (int j = 0; j < 4; j++) {
            int col = n0 + n_base + j * 16 + row16;
            float bsv = bias[col];
#pragma unroll
            for (int r = 0; r < 4; r++) {
                int row = m0 + m_base + i * 16 + quad * 4 + r;
                float val = acc[i][j][r] + bsv;
                if (RESID) val += resid[(size_t)row * N + col];
                if (RELU) val = fmaxf(val, 0.0f);
                size_t caddr = KREMAP
                    ? ((size_t)(row >> 2) * KSTR + (size_t)(row & 3) * 512 + col)
                    : ((size_t)row * N + col);
                stfl(&C[caddr], val);
            }
        }
    }
}

// ---------- transpose: in[(key*4+b)*512 + c] -> out[(b*512+c)*VSTR + key] ----------
__global__ __launch_bounds__(256) void transpose_kv(const bf16_t* __restrict__ kb,
                                                    bf16_t* __restrict__ kT) {
    __shared__ bf16_t tile[64][80];
    const int kt = blockIdx.x * 64;
    const int ct = blockIdx.y * 64;
    const int b  = blockIdx.z;
    const int t = threadIdx.x;
    {
        int kl = t >> 2, cl = (t & 3) * 16;
        const bf16_t* src = kb + ((size_t)(kt + kl) * 4 + b) * 512 + ct + cl;
        *(uint4*)&tile[kl][cl]     = *(const uint4*)src;
        *(uint4*)&tile[kl][cl + 8] = *(const uint4*)(src + 8);
    }
    __syncthreads();
    {
        int cl2 = t >> 2, ks = (t & 3) * 16;
        __attribute__((aligned(16))) bf16_t vals[16];
#pragma unroll
        for (int j = 0; j < 16; j++) vals[j] = tile[ks + j][cl2];
        bf16_t* dst = kT + ((size_t)b * 512 + ct + cl2) * VSTR + kt + ks;
        *(uint4*)dst       = *(const uint4*)&vals[0];
        *(uint4*)(dst + 8) = *(const uint4*)&vals[8];
    }
}

// ---------- MFMA flash attention v4: 1 block = 1 q-tile, all 8 heads ----------
// R2 post-mortem: kernel is L2 line-request throughput bound (~11M requests /
// ~64 lines/cy == observed 72us). v4 cuts requests: (a) all 8 heads in one
// block -> head-mean is plain coalesced STORES, not 3.7M fp32 atomics;
// (b) K/V padded strides (KSTR/VSTR) de-alias L2 channels. 8 waves = 8 heads,
// 256 blocks, 126KB dynamic LDS (1 block/CU). No cross-wave O combine needed.
__global__ __launch_bounds__(512, 1) void attn_mfma(
        const bf16_t* __restrict__ qb,   // [2048,512] rows (q*4+b)
        const bf16_t* __restrict__ kb,   // [4096][KSTR] key-padded
        const bf16_t* __restrict__ vT,   // [4][512][VSTR]
        bf16_t* __restrict__ ctx,        // [2048,512]
        float* __restrict__ attn_out) {  // [4][512][4096], pre-zeroed
    extern __shared__ char smem[];
    bf16_t* Ps   = (bf16_t*)smem;                         // [8 heads][8 q][904]
    bf16_t* Qs   = (bf16_t*)(smem + 115712);              // [8 q][520]
    bf16_t* Zrow = (bf16_t*)(smem + 115712 + 8320);       // [904]
    float*  Ls   = (float*)(smem + 115712 + 8320 + 1808); // [8 heads][8 q] 1/l

    const int b  = blockIdx.x & 3;
    const int qt = blockIdx.x >> 2;
    const int q0 = qt * 8;
    const int tid = threadIdx.x;
    const int lane = tid & 63;
    const int h = tid >> 6;          // wave = head 0..7
    const int hoffg = h * HEADDIM;
    const int row16 = lane & 15;
    const int quad = lane >> 4;

    int us; { int s = q0 * 8, e = s + 827; if (e > 4095) s = 3268; us = s; }
    int sq[4], eq[4];
#pragma unroll
    for (int r = 0; r < 4; r++) {
        int ql = quad * 4 + r;
        if (ql < 8) {
            int s = (q0 + ql) * 8, e = s + 827;
            if (e > 4095) { s = 3268; e = 4096; }
            sq[r] = s; eq[r] = e;
        } else { sq[r] = 0; eq[r] = 0; }
    }

    {   // stage Q: 8 rows x 512 cols (16B per thread)
        int r = tid >> 6, coff = (tid & 63) * 8;
        *(uint4*)&Qs[r * 520 + coff] =
            *(const uint4*)(qb + ((size_t)(q0 + r) * 4 + b) * 512 + coff);
        if (tid < 113) { uint4 z = {0, 0, 0, 0}; *(uint4*)&Zrow[tid * 8] = z; }
    }
    __syncthreads();

    const bf16_t* q0p = (row16 < 8) ? &Qs[row16 * 520 + hoffg + quad * 8] : &Zrow[0];
    const bf16_t* q1p = (row16 < 8) ? &Qs[row16 * 520 + hoffg + 32 + quad * 8] : &Zrow[8];
    const bf16x8 aq0 = *(const bf16x8*)q0p;
    const bf16x8 aq1 = *(const bf16x8*)q1p;

    // ---- QK phase: full 896-key window, 56 iterations ----
    float l[4] = {0.f, 0.f, 0.f, 0.f};
#pragma unroll 4
    for (int it = 0; it < 56; ++it) {
        int key = us + it * 16 + row16;
        int key_eff = key > 4095 ? 4095 : key;
        const bf16_t* kr = kb + (size_t)key_eff * KSTR + b * 512 + hoffg;
        bf16x8 bk0 = *(const bf16x8*)(kr + quad * 8);
        bf16x8 bk1 = *(const bf16x8*)(kr + 32 + quad * 8);
        f32x4 acc = {};
        acc = __builtin_amdgcn_mfma_f32_16x16x32_bf16(aq0, bk0, acc, 0, 0, 0);
        acc = __builtin_amdgcn_mfma_f32_16x16x32_bf16(aq1, bk1, acc, 0, 0, 0);
#pragma unroll
        for (int r = 0; r < 4; r++) {
            int ql = quad * 4 + r;
            bool valid = (key >= sq[r]) && (key < eq[r]);
            float p = valid ? __expf(0.125f * acc[r]) : 0.0f;
            l[r] += p;
            if (ql < 8) Ps[(h * 8 + ql) * 904 + it * 16 + row16] = __float2bfloat16(p);
        }
    }
#pragma unroll
    for (int off = 1; off < 16; off <<= 1) {
#pragma unroll
        for (int r = 0; r < 4; r++) l[r] += __shfl_xor(l[r], off, 64);
    }
    float linv[4];
#pragma unroll
    for (int r = 0; r < 4; r++) linv[r] = 1.0f / l[r];
    if (row16 == 0) {
#pragma unroll
        for (int r = 0; r < 4; r++) {
            int ql = quad * 4 + r;
            if (ql < 8) Ls[h * 8 + ql] = linv[r];
        }
    }
    __syncthreads();   // all heads' Ps + Ls visible

    // ---- PV phase: full 28 iterations, own head's Ps ----
    f32x4 o[4] = {};
#pragma unroll 2
    for (int it = 0; it < 28; ++it) {
        const bf16_t* ap_src = (row16 < 8) ? &Ps[(h * 8 + row16) * 904 + it * 32 + quad * 8]
                                           : &Zrow[0];
        bf16x8 ap = *(const bf16x8*)ap_src;
#pragma unroll
        for (int nt = 0; nt < 4; ++nt) {
            const bf16_t* vr = vT + ((size_t)(b * 512 + hoffg + nt * 16 + row16)) * VSTR
                               + us + it * 32 + quad * 8;
            bf16x8 bv = *(const bf16x8*)vr;
            o[nt] = __builtin_amdgcn_mfma_f32_16x16x32_bf16(ap, bv, o[nt], 0, 0, 0);
        }
    }

    // ---- attn_out head-mean: plain coalesced stores (single writer per row) ----
    {
        int qq = h;                    // wave qq handles q-row q0+qq
        float ls[8];
#pragma unroll
        for (int hh = 0; hh < 8; ++hh) ls[hh] = 0.125f * Ls[hh * 8 + qq];
        float* base = attn_out + ((size_t)b * LQ + q0 + qq) * LK + us;
        const int cmax = LK - us;
        for (int col = lane; col < 896; col += 64) {
            if (col < cmax) {
                float s = 0.f;
#pragma unroll
                for (int hh = 0; hh < 8; ++hh) s += ls[hh] * tofl(Ps[(hh * 8 + qq) * 904 + col]);
                base[col] = s;
            }
        }
    }

    // ---- ctx write (own head, no cross-wave combine) ----
#pragma unroll
    for (int nt = 0; nt < 4; nt++) {
#pragma unroll
        for (int r = 0; r < 4; r++) {
            int ql = quad * 4 + r;
            if (ql < 8) {
                ctx[((size_t)(q0 + ql) * 4 + b) * 512 + hoffg + nt * 16 + row16] =
                    __float2bfloat16(o[nt][r] * linv[r]);
            }
        }
    }
}

extern "C" void kernel_launch(void* const* d_in, const int* in_sizes, int n_in,
                              void* d_out, int out_size, void* d_ws, size_t ws_size,
                              hipStream_t stream) {
    const float* tgt    = (const float*)d_in[0];
    const float* memory = (const float*)d_in[1];
    const float* Wq = (const float*)d_in[2];
    const float* bq = (const float*)d_in[3];
    const float* Wk = (const float*)d_in[4];
    const float* bk = (const float*)d_in[5];
    const float* Wv = (const float*)d_in[6];
    const float* bv = (const float*)d_in[7];
    const float* Wo = (const float*)d_in[8];
    const float* bo = (const float*)d_in[9];
    const float* W1 = (const float*)d_in[10];
    const float* b1 = (const float*)d_in[11];
    const float* W2 = (const float*)d_in[12];
    const float* b2 = (const float*)d_in[13];
    const float* ln1w = (const float*)d_in[14];
    const float* ln1b = (const float*)d_in[15];
    const float* ln2w = (const float*)d_in[16];
    const float* ln2b = (const float*)d_in[17];
    const float* ln3w = (const float*)d_in[18];
    const float* ln3b = (const float*)d_in[19];
    const float* ln4w = (const float*)d_in[20];
    const float* ln4b = (const float*)d_in[21];

    const size_t M1 = (size_t)LQ * BATCH;      // 2048
    const size_t M2 = (size_t)LK * BATCH;      // 16384
    const size_t SZ1 = M1 * DMODEL;

    // ---- workspace map (64 MiB, lifetime-aliased; padded K/vT) ----
    char* wsb = (char*)d_ws;
    const size_t MB = 1 << 20;
    bf16_t* m_buf   = (bf16_t*)(wsb + 0 * MB);   // [2->5], 16MB
    bf16_t* vT_buf  = (bf16_t*)(wsb + 0 * MB);   // [6->7], 16.07MB (m dead)
    bf16_t* h_buf   = (bf16_t*)(wsb + 0 * MB);   // [10->11], 8MB (vT dead)
    bf16_t* k_buf   = (bf16_t*)(wsb + 17 * MB);  // [4->7], 16.13MB padded
    float*  xres    = (float*)(wsb + 17 * MB);   // [8->9], 4MB (k dead)
    float*  xln_f   = (float*)(wsb + 21 * MB);   // [9->11], 4MB
    float*  x2_buf  = (float*)(wsb + 25 * MB);   // [11->12], 4MB
    bf16_t* W2_bf   = (bf16_t*)(wsb + 34 * MB);  // [6.5->11], 2MB (v region head, v dead)
    bf16_t* v_buf   = (bf16_t*)(wsb + 34 * MB);  // [5->6], 16MB
    bf16_t* t_bf    = (bf16_t*)(wsb + 50 * MB);  // [2->3], 2MB
    bf16_t* xln_bf  = (bf16_t*)(wsb + 50 * MB);  // [9->10], 2MB (t_bf dead)
    float*  t_f32   = (float*)(wsb + 52 * MB);   // [2->8], 4MB
    bf16_t* q_bf    = (bf16_t*)(wsb + 56 * MB);  // [3->7], 2MB
    bf16_t* ctx_buf = (bf16_t*)(wsb + 58 * MB);  // [7->8], 2MB
    bf16_t* wqkvo   = (bf16_t*)(wsb + 60 * MB);  // [1->8], 2MB
    bf16_t* W1_bf   = (bf16_t*)(wsb + 62 * MB);  // [1->10], 2MB

    bf16_t* Wq_bf = wqkvo;
    bf16_t* Wk_bf = wqkvo + 262144;
    bf16_t* Wv_bf = wqkvo + 2 * 262144;
    bf16_t* Wo_bf = wqkvo + 3 * 262144;

    float* out_x    = (float*)d_out;
    float* out_attn = out_x + SZ1;

    // 1. qkvo + W1 conversions + attn_out zero
    prep_kernel<<<dim3(10240), dim3(256), 0, stream>>>(
        Wq, Wk, Wv, Wo, W1, wqkvo, W1_bf, out_attn);

    // 2. LN1 (dual) + LN2 fused
    ln12_kernel<<<dim3(M1 + M2), dim3(256), 0, stream>>>(
        tgt, memory, ln1w, ln1b, ln2w, ln2b, t_bf, t_f32, m_buf);

    // 3-5. projections (K-proj writes padded k_buf layout)
    gemm_mfma<64, bf16_t, false, false><<<dim3(8, 16), dim3(256), 0, stream>>>(
        t_bf, Wq_bf, bq, nullptr, q_bf, M1, DMODEL, DMODEL);
    gemm_mfma<128, bf16_t, false, false, true><<<dim3(4, 128), dim3(256), 0, stream>>>(
        m_buf, Wk_bf, bk, nullptr, k_buf, M2, DMODEL, DMODEL);
    gemm_mfma<128, bf16_t, false, false><<<dim3(4, 128), dim3(256), 0, stream>>>(
        m_buf, Wv_bf, bv, nullptr, v_buf, M2, DMODEL, DMODEL);

    // 6. V transpose to padded [b][d][VSTR] (m_buf dead -> vT region)
    transpose_kv<<<dim3(64, 8, 4), dim3(256), 0, stream>>>(v_buf, vT_buf);

    // 6.5 W2 conversion into dead v_buf head
    conv_w2<<<dim3(1024), dim3(256), 0, stream>>>(W2, W2_bf);

    // 7. attention: 256 blocks x 8 waves (= 8 heads), 126KB dynamic LDS
    const int attn_lds = 115712 + 8320 + 1808 + 256;   // 126096 B
    hipFuncSetAttribute((const void*)attn_mfma,
                        hipFuncAttributeMaxDynamicSharedMemorySize, attn_lds);
    attn_mfma<<<dim3(256), dim3(512), attn_lds, stream>>>(
        q_bf, k_buf, vT_buf, ctx_buf, out_attn);

    // 8. out proj + residual(t) -> xres (k_buf region, dead)
    gemm_mfma<64, float, false, true><<<dim3(8, 16), dim3(256), 0, stream>>>(
        ctx_buf, Wo_bf, bo, t_f32, xres, M1, DMODEL, DMODEL);

    // 9. LN3 (dual)
    ln_kernel<bf16_t, true><<<dim3(M1), dim3(256), 0, stream>>>(xres, ln3w, ln3b, xln_bf, xln_f);

    // 10. FF1 (relu)
    gemm_mfma<128, bf16_t, true, false><<<dim3(16, 16), dim3(256), 0, stream>>>(
        xln_bf, W1_bf, b1, nullptr, h_buf, M1, DFF, DMODEL);

    // 11. FF2 + residual(xln)
    gemm_mfma<64, float, false, true><<<dim3(8, 16), dim3(256), 0, stream>>>(
        h_buf, W2_bf, b2, xln_f, x2_buf, M1, DMODEL, DFF);

    // 12. LN4 -> fp32 out
    ln_kernel<float, false><<<dim3(M1), dim3(256), 0, stream>>>(x2_buf, ln4w, ln4b, out_x, nullptr);
}

// Round 4
// 317.610 us; speedup vs baseline: 1.1246x; 1.0237x over previous
//
#include <hip/hip_runtime.h>
#include <hip/hip_bf16.h>

typedef __hip_bfloat16 bf16_t;
typedef __bf16 bf16x8 __attribute__((ext_vector_type(8)));
typedef float f32x4 __attribute__((ext_vector_type(4)));

#define LQ 512
#define LK 4096
#define BATCH 4
#define DMODEL 512
#define NHEAD 8
#define HEADDIM 64
#define DFF 2048
#define LN_EPS 1e-5f

// padded strides: 64B-aligned rows (no line straddle), rotate 64B/row mod 4KB
#define KSTR 2080   // elements per key in k_buf: 4160B/key
#define VSTR 4128   // elements per (b,c) row in vT: 8256B/row

__device__ inline float tofl(float x) { return x; }
__device__ inline float tofl(bf16_t x) { return __bfloat162float(x); }
__device__ inline void stfl(float* p, float v) { *p = v; }
__device__ inline void stfl(bf16_t* p, float v) { *p = __float2bfloat16(v); }

// async global->LDS 16B copy: LDS dest = wave-uniform base + lane*16
__device__ __forceinline__ void gld_lds16(const bf16_t* g, void* lds_base) {
    __builtin_amdgcn_global_load_lds(
        (const __attribute__((address_space(1))) uint32_t*)g,
        (__attribute__((address_space(3))) uint32_t*)lds_base, 16, 0, 0);
}

// ---------- prep: Wq/Wk/Wv/Wo + W1 conversions ----------
__global__ void prep_kernel(const float* __restrict__ s0, const float* __restrict__ s1,
                            const float* __restrict__ s2, const float* __restrict__ s3,
                            const float* __restrict__ s4,
                            bf16_t* __restrict__ wqkvo, bf16_t* __restrict__ w1bf) {
    int t = blockIdx.x * 256 + threadIdx.x;
    int which = t >> 16;            // 0..7, 262144 elements each
    int idx = (t & 65535) * 4;
    const float* s; bf16_t* d;
    if (which < 4) {
        s = (which == 0 ? s0 : which == 1 ? s1 : which == 2 ? s2 : s3);
        d = wqkvo + (size_t)which * 262144;
    } else {
        s = s4 + (size_t)(which - 4) * 262144;
        d = w1bf + (size_t)(which - 4) * 262144;
    }
    float4 v = *(const float4*)(s + idx);
    d[idx + 0] = __float2bfloat16(v.x);
    d[idx + 1] = __float2bfloat16(v.y);
    d[idx + 2] = __float2bfloat16(v.z);
    d[idx + 3] = __float2bfloat16(v.w);
}

// ---------- W2 conversion (runs after transpose; lands in dead v_buf region) ----------
__global__ void conv_w2(const float* __restrict__ s, bf16_t* __restrict__ d) {
    int i = (blockIdx.x * 256 + threadIdx.x) * 4;
    float4 v = *(const float4*)(s + i);
    d[i + 0] = __float2bfloat16(v.x);
    d[i + 1] = __float2bfloat16(v.y);
    d[i + 2] = __float2bfloat16(v.z);
    d[i + 3] = __float2bfloat16(v.w);
}

// ---------- LayerNorm (generic, templated) ----------
template <typename TOUT, bool DUAL>
__global__ void ln_kernel(const float* __restrict__ in, const float* __restrict__ w,
                          const float* __restrict__ b, TOUT* __restrict__ out1,
                          float* __restrict__ out2) {
    __shared__ float red[256];
    const int row = blockIdx.x;
    const int tid = threadIdx.x;
    const float* x = in + (size_t)row * DMODEL;
    float v0 = x[tid];
    float v1 = x[tid + 256];

    red[tid] = v0 + v1;
    __syncthreads();
    for (int s = 128; s > 0; s >>= 1) { if (tid < s) red[tid] += red[tid + s]; __syncthreads(); }
    float mu = red[0] * (1.0f / DMODEL);
    __syncthreads();

    float d0 = v0 - mu, d1 = v1 - mu;
    red[tid] = d0 * d0 + d1 * d1;
    __syncthreads();
    for (int s = 128; s > 0; s >>= 1) { if (tid < s) red[tid] += red[tid + s]; __syncthreads(); }
    float inv = rsqrtf(red[0] * (1.0f / DMODEL) + LN_EPS);

    float r0 = d0 * inv * w[tid] + b[tid];
    float r1 = d1 * inv * w[tid + 256] + b[tid + 256];
    TOUT* o = out1 + (size_t)row * DMODEL;
    stfl(&o[tid], r0);
    stfl(&o[tid + 256], r1);
    if (DUAL) {
        float* o2 = out2 + (size_t)row * DMODEL;
        o2[tid] = r0;
        o2[tid + 256] = r1;
    }
}

// ---------- fused LN1 + LN2 ----------
__global__ void ln12_kernel(const float* __restrict__ tgt, const float* __restrict__ memory,
                            const float* __restrict__ w1, const float* __restrict__ b1,
                            const float* __restrict__ w2, const float* __restrict__ b2,
                            bf16_t* __restrict__ t_bf, float* __restrict__ t_f32,
                            bf16_t* __restrict__ m_buf) {
    __shared__ float red[256];
    const int row = blockIdx.x;
    const int tid = threadIdx.x;
    const float* in; const float* w; const float* b;
    bf16_t* o1; float* o2; bool dual;
    if (row < 2048) {
        in = tgt + (size_t)row * DMODEL; w = w1; b = b1;
        o1 = t_bf + (size_t)row * DMODEL; o2 = t_f32 + (size_t)row * DMODEL; dual = true;
    } else {
        int r2 = row - 2048;
        in = memory + (size_t)r2 * DMODEL; w = w2; b = b2;
        o1 = m_buf + (size_t)r2 * DMODEL; o2 = nullptr; dual = false;
    }
    float v0 = in[tid];
    float v1 = in[tid + 256];
    red[tid] = v0 + v1;
    __syncthreads();
    for (int s = 128; s > 0; s >>= 1) { if (tid < s) red[tid] += red[tid + s]; __syncthreads(); }
    float mu = red[0] * (1.0f / DMODEL);
    __syncthreads();
    float d0 = v0 - mu, d1 = v1 - mu;
    red[tid] = d0 * d0 + d1 * d1;
    __syncthreads();
    for (int s = 128; s > 0; s >>= 1) { if (tid < s) red[tid] += red[tid + s]; __syncthreads(); }
    float inv = rsqrtf(red[0] * (1.0f / DMODEL) + LN_EPS);
    float r0 = d0 * inv * w[tid] + b[tid];
    float r1 = d1 * inv * w[tid + 256] + b[tid + 256];
    o1[tid] = __float2bfloat16(r0);
    o1[tid + 256] = __float2bfloat16(r1);
    if (dual) {
        o2[tid] = r0;
        o2[tid + 256] = r1;
    }
}

// ---------- MFMA GEMM, coalesced+swizzled global_load_lds staging ----------
// KREMAP: C-write goes to the key-padded k_buf layout (row=key*4+b ->
//   addr = key*KSTR + b*512 + col) to break 4KB channel aliasing in attn.
template <int TN, typename TC, bool RELU, bool RESID, bool KREMAP = false>
__global__ __launch_bounds__(256) void gemm_mfma(
        const bf16_t* __restrict__ A, const bf16_t* __restrict__ B,
        const float* __restrict__ bias, const float* __restrict__ resid,
        TC* __restrict__ C, int M, int N, int K) {
    __shared__ uint4 As4[1024];          // 128 rows x 8 chunks
    __shared__ uint4 Bs4[TN * 8];        // TN rows x 8 chunks

    const int tid = threadIdx.x;
    const int lane = tid & 63;
    const int wave = tid >> 6;
    const int row16 = lane & 15;
    const int quad = lane >> 4;
    const int n0 = blockIdx.x * TN;
    const int m0 = blockIdx.y * 128;

    constexpr int MI = (TN == 128) ? 4 : 2;           // 16-row frags per wave in M
    const int wy = (TN == 128) ? (wave >> 1) : wave;
    const int wx = (TN == 128) ? (wave & 1) : 0;
    const int m_base = wy * ((TN == 128) ? 64 : 32);
    const int n_base = wx * 64;

    const int rr = lane >> 3;            // 0..7 (row within issue)
    const int kc = (lane & 7) ^ rr;      // swizzled global k-chunk
    const int kx = row16 & 7;            // frag-read deswizzle key

    const bf16_t* AsE = (const bf16_t*)As4;
    const bf16_t* BsE = (const bf16_t*)Bs4;

    f32x4 acc[MI][4] = {};

    for (int k0 = 0; k0 < K; k0 += 64) {
        // stage A: 16 issues x 8 rows
#pragma unroll
        for (int it = 0; it < 4; it++) {
            int issue = it * 4 + wave;
            int r = issue * 8 + rr;
            gld_lds16(A + (size_t)(m0 + r) * K + k0 + kc * 8, &As4[issue * 64]);
        }
        // stage B: TN/8 issues
#pragma unroll
        for (int it = 0; it < TN / 32; it++) {
            int issue = it * 4 + wave;
            int r = issue * 8 + rr;
            gld_lds16(B + (size_t)(n0 + r) * K + k0 + kc * 8, &Bs4[issue * 64]);
        }
        __syncthreads();
#pragma unroll
        for (int s = 0; s < 2; s++) {
            const int kq = s * 4 + quad;
            const int kcs = (kq ^ kx) * 8;
            bf16x8 af[MI], bfr[4];
#pragma unroll
            for (int i = 0; i < MI; i++)
                af[i] = *(const bf16x8*)&AsE[(m_base + i * 16 + row16) * 64 + kcs];
#pragma unroll
            for (int j = 0; j < 4; j++)
                bfr[j] = *(const bf16x8*)&BsE[(n_base + j * 16 + row16) * 64 + kcs];
#pragma unroll
            for (int i = 0; i < MI; i++)
#pragma unroll
                for (int j = 0; j < 4; j++)
                    acc[i][j] = __builtin_amdgcn_mfma_f32_16x16x32_bf16(af[i], bfr[j], acc[i][j], 0, 0, 0);
        }
        __syncthreads();
    }

#pragma unroll
    for (int i = 0; i < MI; i++) {
#pragma unroll
        for (int j = 0; j < 4; j++) {
            int col = n0 + n_base + j * 16 + row16;
            float bsv = bias[col];
#pragma unroll
            for (int r = 0; r < 4; r++) {
                int row = m0 + m_base + i * 16 + quad * 4 + r;
                float val = acc[i][j][r] + bsv;
                if (RESID) val += resid[(size_t)row * N + col];
                if (RELU) val = fmaxf(val, 0.0f);
                size_t caddr = KREMAP
                    ? ((size_t)(row >> 2) * KSTR + (size_t)(row & 3) * 512 + col)
                    : ((size_t)row * N + col);
                stfl(&C[caddr], val);
            }
        }
    }
}

// ---------- transpose: in[(key*4+b)*512 + c] -> out[(b*512+c)*VSTR + key] ----------
__global__ __launch_bounds__(256) void transpose_kv(const bf16_t* __restrict__ kb,
                                                    bf16_t* __restrict__ kT) {
    __shared__ bf16_t tile[64][80];
    const int kt = blockIdx.x * 64;
    const int ct = blockIdx.y * 64;
    const int b  = blockIdx.z;
    const int t = threadIdx.x;
    {
        int kl = t >> 2, cl = (t & 3) * 16;
        const bf16_t* src = kb + ((size_t)(kt + kl) * 4 + b) * 512 + ct + cl;
        *(uint4*)&tile[kl][cl]     = *(const uint4*)src;
        *(uint4*)&tile[kl][cl + 8] = *(const uint4*)(src + 8);
    }
    __syncthreads();
    {
        int cl2 = t >> 2, ks = (t & 3) * 16;
        __attribute__((aligned(16))) bf16_t vals[16];
#pragma unroll
        for (int j = 0; j < 16; j++) vals[j] = tile[ks + j][cl2];
        bf16_t* dst = kT + ((size_t)b * 512 + ct + cl2) * VSTR + kt + ks;
        *(uint4*)dst       = *(const uint4*)&vals[0];
        *(uint4*)(dst + 8) = *(const uint4*)&vals[8];
    }
}

// ---------- MFMA flash attention v5: XCD-local batches, aligned pads ----------
// R3 post-mortem: KSTR/VSTR pads of 32B broke 64B line alignment (odd rows
// straddle -> 1.25x lines, FETCH 78MB) and b=blk&3 spread all batches over
// every XCD (L2 thrash; R1's b=(blk&7)>>1 had kept FETCH at 21MB). v5:
// 64B-multiple pads; b derived from blk&7 so each XCD touches ONE batch's
// K (4MB, L2-fits) in QK and one vT (4.1MB) in PV; attn_out zero-fill folded
// into the (single-writer) row stores.
__global__ __launch_bounds__(512, 1) void attn_mfma(
        const bf16_t* __restrict__ qb,   // [2048,512] rows (q*4+b)
        const bf16_t* __restrict__ kb,   // [4096][KSTR] key-padded
        const bf16_t* __restrict__ vT,   // [4][512][VSTR]
        bf16_t* __restrict__ ctx,        // [2048,512]
        float* __restrict__ attn_out) {  // [4][512][4096], written in full here
    extern __shared__ char smem[];
    bf16_t* Ps   = (bf16_t*)smem;                         // [8 heads][8 q][904]
    bf16_t* Qs   = (bf16_t*)(smem + 115712);              // [8 q][520]
    bf16_t* Zrow = (bf16_t*)(smem + 115712 + 8320);       // [904]
    float*  Ls   = (float*)(smem + 115712 + 8320 + 1808); // [8 heads][8 q] 1/l

    const int blk = blockIdx.x;
    const int b  = (blk & 7) >> 1;                 // batch locked to XCD pair
    const int qt = ((blk >> 3) << 1) | (blk & 1);  // 0..63
    const int q0 = qt * 8;
    const int tid = threadIdx.x;
    const int lane = tid & 63;
    const int h = tid >> 6;          // wave = head 0..7
    const int hoffg = h * HEADDIM;
    const int row16 = lane & 15;
    const int quad = lane >> 4;

    int us; { int s = q0 * 8, e = s + 827; if (e > 4095) s = 3268; us = s; }
    int sq[4], eq[4];
#pragma unroll
    for (int r = 0; r < 4; r++) {
        int ql = quad * 4 + r;
        if (ql < 8) {
            int s = (q0 + ql) * 8, e = s + 827;
            if (e > 4095) { s = 3268; e = 4096; }
            sq[r] = s; eq[r] = e;
        } else { sq[r] = 0; eq[r] = 0; }
    }

    {   // stage Q: 8 rows x 512 cols (16B per thread)
        int r = tid >> 6, coff = (tid & 63) * 8;
        *(uint4*)&Qs[r * 520 + coff] =
            *(const uint4*)(qb + ((size_t)(q0 + r) * 4 + b) * 512 + coff);
        if (tid < 113) { uint4 z = {0, 0, 0, 0}; *(uint4*)&Zrow[tid * 8] = z; }
    }
    __syncthreads();

    const bf16_t* q0p = (row16 < 8) ? &Qs[row16 * 520 + hoffg + quad * 8] : &Zrow[0];
    const bf16_t* q1p = (row16 < 8) ? &Qs[row16 * 520 + hoffg + 32 + quad * 8] : &Zrow[8];
    const bf16x8 aq0 = *(const bf16x8*)q0p;
    const bf16x8 aq1 = *(const bf16x8*)q1p;

    // ---- QK phase: full 896-key window, 56 iterations ----
    float l[4] = {0.f, 0.f, 0.f, 0.f};
#pragma unroll 4
    for (int it = 0; it < 56; ++it) {
        int key = us + it * 16 + row16;
        int key_eff = key > 4095 ? 4095 : key;
        const bf16_t* kr = kb + (size_t)key_eff * KSTR + b * 512 + hoffg;
        bf16x8 bk0 = *(const bf16x8*)(kr + quad * 8);
        bf16x8 bk1 = *(const bf16x8*)(kr + 32 + quad * 8);
        f32x4 acc = {};
        acc = __builtin_amdgcn_mfma_f32_16x16x32_bf16(aq0, bk0, acc, 0, 0, 0);
        acc = __builtin_amdgcn_mfma_f32_16x16x32_bf16(aq1, bk1, acc, 0, 0, 0);
#pragma unroll
        for (int r = 0; r < 4; r++) {
            int ql = quad * 4 + r;
            bool valid = (key >= sq[r]) && (key < eq[r]);
            float p = valid ? __expf(0.125f * acc[r]) : 0.0f;
            l[r] += p;
            if (ql < 8) Ps[(h * 8 + ql) * 904 + it * 16 + row16] = __float2bfloat16(p);
        }
    }
#pragma unroll
    for (int off = 1; off < 16; off <<= 1) {
#pragma unroll
        for (int r = 0; r < 4; r++) l[r] += __shfl_xor(l[r], off, 64);
    }
    float linv[4];
#pragma unroll
    for (int r = 0; r < 4; r++) linv[r] = 1.0f / l[r];
    if (row16 == 0) {
#pragma unroll
        for (int r = 0; r < 4; r++) {
            int ql = quad * 4 + r;
            if (ql < 8) Ls[h * 8 + ql] = linv[r];
        }
    }
    __syncthreads();   // all heads' Ps + Ls visible

    // ---- PV phase: full 28 iterations, own head's Ps ----
    f32x4 o[4] = {};
#pragma unroll 2
    for (int it = 0; it < 28; ++it) {
        const bf16_t* ap_src = (row16 < 8) ? &Ps[(h * 8 + row16) * 904 + it * 32 + quad * 8]
                                           : &Zrow[0];
        bf16x8 ap = *(const bf16x8*)ap_src;
#pragma unroll
        for (int nt = 0; nt < 4; ++nt) {
            const bf16_t* vr = vT + ((size_t)(b * 512 + hoffg + nt * 16 + row16)) * VSTR
                               + us + it * 32 + quad * 8;
            bf16x8 bv = *(const bf16x8*)vr;
            o[nt] = __builtin_amdgcn_mfma_f32_16x16x32_bf16(ap, bv, o[nt], 0, 0, 0);
        }
    }

    // ---- attn_out head-mean: full-row stores (zeros outside window) ----
    {
        int qq = h;                    // wave qq owns q-row q0+qq entirely
        float ls[8];
#pragma unroll
        for (int hh = 0; hh < 8; ++hh) ls[hh] = 0.125f * Ls[hh * 8 + qq];
        float* rowp = attn_out + ((size_t)b * LQ + q0 + qq) * LK;
        const bf16_t* ps = Ps + qq * 904;
        // 4096 cols = 1024 float4 = 64 lanes x 16 iters
        for (int it = 0; it < 16; ++it) {
            int c4 = (it * 64 + lane) * 4;          // first col of this float4
            float4 v = {0.f, 0.f, 0.f, 0.f};
            int off = c4 - us;                      // Ps col of element 0
            if (off >= -3 && off < 896) {
#pragma unroll
                for (int e = 0; e < 4; ++e) {
                    int pc = off + e;
                    float s = 0.f;
                    if (pc >= 0 && pc < 896) {
#pragma unroll
                        for (int hh = 0; hh < 8; ++hh)
                            s += ls[hh] * tofl(ps[hh * 8 * 904 + pc]);
                    }
                    (&v.x)[e] = s;
                }
            }
            *(float4*)(rowp + c4) = v;
        }
    }

    // ---- ctx write (own head, no cross-wave combine) ----
#pragma unroll
    for (int nt = 0; nt < 4; nt++) {
#pragma unroll
        for (int r = 0; r < 4; r++) {
            int ql = quad * 4 + r;
            if (ql < 8) {
                ctx[((size_t)(q0 + ql) * 4 + b) * 512 + hoffg + nt * 16 + row16] =
                    __float2bfloat16(o[nt][r] * linv[r]);
            }
        }
    }
}

extern "C" void kernel_launch(void* const* d_in, const int* in_sizes, int n_in,
                              void* d_out, int out_size, void* d_ws, size_t ws_size,
                              hipStream_t stream) {
    const float* tgt    = (const float*)d_in[0];
    const float* memory = (const float*)d_in[1];
    const float* Wq = (const float*)d_in[2];
    const float* bq = (const float*)d_in[3];
    const float* Wk = (const float*)d_in[4];
    const float* bk = (const float*)d_in[5];
    const float* Wv = (const float*)d_in[6];
    const float* bv = (const float*)d_in[7];
    const float* Wo = (const float*)d_in[8];
    const float* bo = (const float*)d_in[9];
    const float* W1 = (const float*)d_in[10];
    const float* b1 = (const float*)d_in[11];
    const float* W2 = (const float*)d_in[12];
    const float* b2 = (const float*)d_in[13];
    const float* ln1w = (const float*)d_in[14];
    const float* ln1b = (const float*)d_in[15];
    const float* ln2w = (const float*)d_in[16];
    const float* ln2b = (const float*)d_in[17];
    const float* ln3w = (const float*)d_in[18];
    const float* ln3b = (const float*)d_in[19];
    const float* ln4w = (const float*)d_in[20];
    const float* ln4b = (const float*)d_in[21];

    const size_t M1 = (size_t)LQ * BATCH;      // 2048
    const size_t M2 = (size_t)LK * BATCH;      // 16384
    const size_t SZ1 = M1 * DMODEL;

    // ---- workspace map (64 MiB, lifetime-aliased; padded K/vT) ----
    char* wsb = (char*)d_ws;
    const size_t MB = 1 << 20;
    bf16_t* m_buf   = (bf16_t*)(wsb + 0 * MB);   // [2->5], 16MB
    bf16_t* vT_buf  = (bf16_t*)(wsb + 0 * MB);   // [6->7], 16.13MB (m dead)
    bf16_t* h_buf   = (bf16_t*)(wsb + 0 * MB);   // [10->11], 8MB (vT dead)
    bf16_t* k_buf   = (bf16_t*)(wsb + 17 * MB);  // [4->7], 16.25MB padded
    float*  xres    = (float*)(wsb + 17 * MB);   // [8->9], 4MB (k dead)
    float*  xln_f   = (float*)(wsb + 21 * MB);   // [9->11], 4MB
    float*  x2_buf  = (float*)(wsb + 25 * MB);   // [11->12], 4MB
    bf16_t* W2_bf   = (bf16_t*)(wsb + 34 * MB);  // [6.5->11], 2MB (v region head, v dead)
    bf16_t* v_buf   = (bf16_t*)(wsb + 34 * MB);  // [5->6], 16MB
    bf16_t* t_bf    = (bf16_t*)(wsb + 50 * MB);  // [2->3], 2MB
    bf16_t* xln_bf  = (bf16_t*)(wsb + 50 * MB);  // [9->10], 2MB (t_bf dead)
    float*  t_f32   = (float*)(wsb + 52 * MB);   // [2->8], 4MB
    bf16_t* q_bf    = (bf16_t*)(wsb + 56 * MB);  // [3->7], 2MB
    bf16_t* ctx_buf = (bf16_t*)(wsb + 58 * MB);  // [7->8], 2MB
    bf16_t* wqkvo   = (bf16_t*)(wsb + 60 * MB);  // [1->8], 2MB
    bf16_t* W1_bf   = (bf16_t*)(wsb + 62 * MB);  // [1->10], 2MB

    bf16_t* Wq_bf = wqkvo;
    bf16_t* Wk_bf = wqkvo + 262144;
    bf16_t* Wv_bf = wqkvo + 2 * 262144;
    bf16_t* Wo_bf = wqkvo + 3 * 262144;

    float* out_x    = (float*)d_out;
    float* out_attn = out_x + SZ1;

    // 1. qkvo + W1 conversions (attn_out now fully written by attn itself)
    prep_kernel<<<dim3(2048), dim3(256), 0, stream>>>(
        Wq, Wk, Wv, Wo, W1, wqkvo, W1_bf);

    // 2. LN1 (dual) + LN2 fused
    ln12_kernel<<<dim3(M1 + M2), dim3(256), 0, stream>>>(
        tgt, memory, ln1w, ln1b, ln2w, ln2b, t_bf, t_f32, m_buf);

    // 3-5. projections (K-proj writes padded k_buf layout)
    gemm_mfma<64, bf16_t, false, false><<<dim3(8, 16), dim3(256), 0, stream>>>(
        t_bf, Wq_bf, bq, nullptr, q_bf, M1, DMODEL, DMODEL);
    gemm_mfma<128, bf16_t, false, false, true><<<dim3(4, 128), dim3(256), 0, stream>>>(
        m_buf, Wk_bf, bk, nullptr, k_buf, M2, DMODEL, DMODEL);
    gemm_mfma<128, bf16_t, false, false><<<dim3(4, 128), dim3(256), 0, stream>>>(
        m_buf, Wv_bf, bv, nullptr, v_buf, M2, DMODEL, DMODEL);

    // 6. V transpose to padded [b][d][VSTR] (m_buf dead -> vT region)
    transpose_kv<<<dim3(64, 8, 4), dim3(256), 0, stream>>>(v_buf, vT_buf);

    // 6.5 W2 conversion into dead v_buf head
    conv_w2<<<dim3(1024), dim3(256), 0, stream>>>(W2, W2_bf);

    // 7. attention: 256 blocks x 8 waves (= 8 heads), 126KB dynamic LDS
    const int attn_lds = 115712 + 8320 + 1808 + 256;   // 126096 B
    hipFuncSetAttribute((const void*)attn_mfma,
                        hipFuncAttributeMaxDynamicSharedMemorySize, attn_lds);
    attn_mfma<<<dim3(256), dim3(512), attn_lds, stream>>>(
        q_bf, k_buf, vT_buf, ctx_buf, out_attn);

    // 8. out proj + residual(t) -> xres (k_buf region, dead)
    gemm_mfma<64, float, false, true><<<dim3(8, 16), dim3(256), 0, stream>>>(
        ctx_buf, Wo_bf, bo, t_f32, xres, M1, DMODEL, DMODEL);

    // 9. LN3 (dual)
    ln_kernel<bf16_t, true><<<dim3(M1), dim3(256), 0, stream>>>(xres, ln3w, ln3b, xln_bf, xln_f);

    // 10. FF1 (relu)
    gemm_mfma<128, bf16_t, true, false><<<dim3(16, 16), dim3(256), 0, stream>>>(
        xln_bf, W1_bf, b1, nullptr, h_buf, M1, DFF, DMODEL);

    // 11. FF2 + residual(xln)
    gemm_mfma<64, float, false, true><<<dim3(8, 16), dim3(256), 0, stream>>>(
        h_buf, W2_bf, b2, xln_f, x2_buf, M1, DMODEL, DFF);

    // 12. LN4 -> fp32 out
    ln_kernel<float, false><<<dim3(M1), dim3(256), 0, stream>>>(x2_buf, ln4w, ln4b, out_x, nullptr);
}

// Round 5
// 305.829 us; speedup vs baseline: 1.1680x; 1.0385x over previous
//
#include <hip/hip_runtime.h>
#include <hip/hip_bf16.h>

typedef __hip_bfloat16 bf16_t;
typedef __bf16 bf16x8 __attribute__((ext_vector_type(8)));
typedef float f32x4 __attribute__((ext_vector_type(4)));

#define LQ 512
#define LK 4096
#define BATCH 4
#define DMODEL 512
#define NHEAD 8
#define HEADDIM 64
#define DFF 2048
#define LN_EPS 1e-5f

// padded strides: 64B-aligned rows (no line straddle), rotate 64B/row mod 4KB
#define KSTR 2080   // elements per key in k_buf: 4160B/key
#define VSTR 4128   // elements per (b,c) row in vT: 8256B/row

__device__ inline float tofl(float x) { return x; }
__device__ inline float tofl(bf16_t x) { return __bfloat162float(x); }
__device__ inline void stfl(float* p, float v) { *p = v; }
__device__ inline void stfl(bf16_t* p, float v) { *p = __float2bfloat16(v); }

// async global->LDS 16B copy: LDS dest = wave-uniform base + lane*16
__device__ __forceinline__ void gld_lds16(const bf16_t* g, void* lds_base) {
    __builtin_amdgcn_global_load_lds(
        (const __attribute__((address_space(1))) uint32_t*)g,
        (__attribute__((address_space(3))) uint32_t*)lds_base, 16, 0, 0);
}

// ---------- prep: Wq/Wk/Wv/Wo + W1 conversions ----------
__global__ void prep_kernel(const float* __restrict__ s0, const float* __restrict__ s1,
                            const float* __restrict__ s2, const float* __restrict__ s3,
                            const float* __restrict__ s4,
                            bf16_t* __restrict__ wqkvo, bf16_t* __restrict__ w1bf) {
    int t = blockIdx.x * 256 + threadIdx.x;
    int which = t >> 16;            // 0..7, 262144 elements each
    int idx = (t & 65535) * 4;
    const float* s; bf16_t* d;
    if (which < 4) {
        s = (which == 0 ? s0 : which == 1 ? s1 : which == 2 ? s2 : s3);
        d = wqkvo + (size_t)which * 262144;
    } else {
        s = s4 + (size_t)(which - 4) * 262144;
        d = w1bf + (size_t)(which - 4) * 262144;
    }
    float4 v = *(const float4*)(s + idx);
    d[idx + 0] = __float2bfloat16(v.x);
    d[idx + 1] = __float2bfloat16(v.y);
    d[idx + 2] = __float2bfloat16(v.z);
    d[idx + 3] = __float2bfloat16(v.w);
}

// ---------- W2 conversion (runs after transpose; lands in dead v_buf region) ----------
__global__ void conv_w2(const float* __restrict__ s, bf16_t* __restrict__ d) {
    int i = (blockIdx.x * 256 + threadIdx.x) * 4;
    float4 v = *(const float4*)(s + i);
    d[i + 0] = __float2bfloat16(v.x);
    d[i + 1] = __float2bfloat16(v.y);
    d[i + 2] = __float2bfloat16(v.z);
    d[i + 3] = __float2bfloat16(v.w);
}

// ---------- LayerNorm (generic, templated) ----------
template <typename TOUT, bool DUAL>
__global__ void ln_kernel(const float* __restrict__ in, const float* __restrict__ w,
                          const float* __restrict__ b, TOUT* __restrict__ out1,
                          float* __restrict__ out2) {
    __shared__ float red[256];
    const int row = blockIdx.x;
    const int tid = threadIdx.x;
    const float* x = in + (size_t)row * DMODEL;
    float v0 = x[tid];
    float v1 = x[tid + 256];

    red[tid] = v0 + v1;
    __syncthreads();
    for (int s = 128; s > 0; s >>= 1) { if (tid < s) red[tid] += red[tid + s]; __syncthreads(); }
    float mu = red[0] * (1.0f / DMODEL);
    __syncthreads();

    float d0 = v0 - mu, d1 = v1 - mu;
    red[tid] = d0 * d0 + d1 * d1;
    __syncthreads();
    for (int s = 128; s > 0; s >>= 1) { if (tid < s) red[tid] += red[tid + s]; __syncthreads(); }
    float inv = rsqrtf(red[0] * (1.0f / DMODEL) + LN_EPS);

    float r0 = d0 * inv * w[tid] + b[tid];
    float r1 = d1 * inv * w[tid + 256] + b[tid + 256];
    TOUT* o = out1 + (size_t)row * DMODEL;
    stfl(&o[tid], r0);
    stfl(&o[tid + 256], r1);
    if (DUAL) {
        float* o2 = out2 + (size_t)row * DMODEL;
        o2[tid] = r0;
        o2[tid + 256] = r1;
    }
}

// ---------- fused LN1 + LN2 ----------
__global__ void ln12_kernel(const float* __restrict__ tgt, const float* __restrict__ memory,
                            const float* __restrict__ w1, const float* __restrict__ b1,
                            const float* __restrict__ w2, const float* __restrict__ b2,
                            bf16_t* __restrict__ t_bf, float* __restrict__ t_f32,
                            bf16_t* __restrict__ m_buf) {
    __shared__ float red[256];
    const int row = blockIdx.x;
    const int tid = threadIdx.x;
    const float* in; const float* w; const float* b;
    bf16_t* o1; float* o2; bool dual;
    if (row < 2048) {
        in = tgt + (size_t)row * DMODEL; w = w1; b = b1;
        o1 = t_bf + (size_t)row * DMODEL; o2 = t_f32 + (size_t)row * DMODEL; dual = true;
    } else {
        int r2 = row - 2048;
        in = memory + (size_t)r2 * DMODEL; w = w2; b = b2;
        o1 = m_buf + (size_t)r2 * DMODEL; o2 = nullptr; dual = false;
    }
    float v0 = in[tid];
    float v1 = in[tid + 256];
    red[tid] = v0 + v1;
    __syncthreads();
    for (int s = 128; s > 0; s >>= 1) { if (tid < s) red[tid] += red[tid + s]; __syncthreads(); }
    float mu = red[0] * (1.0f / DMODEL);
    __syncthreads();
    float d0 = v0 - mu, d1 = v1 - mu;
    red[tid] = d0 * d0 + d1 * d1;
    __syncthreads();
    for (int s = 128; s > 0; s >>= 1) { if (tid < s) red[tid] += red[tid + s]; __syncthreads(); }
    float inv = rsqrtf(red[0] * (1.0f / DMODEL) + LN_EPS);
    float r0 = d0 * inv * w[tid] + b[tid];
    float r1 = d1 * inv * w[tid + 256] + b[tid + 256];
    o1[tid] = __float2bfloat16(r0);
    o1[tid + 256] = __float2bfloat16(r1);
    if (dual) {
        o2[tid] = r0;
        o2[tid + 256] = r1;
    }
}

// ---------- MFMA GEMM, coalesced+swizzled global_load_lds staging ----------
// KREMAP: C-write goes to the key-padded k_buf layout (row=key*4+b ->
//   addr = key*KSTR + b*512 + col) to break 4KB channel aliasing in attn.
template <int TN, typename TC, bool RELU, bool RESID, bool KREMAP = false>
__global__ __launch_bounds__(256) void gemm_mfma(
        const bf16_t* __restrict__ A, const bf16_t* __restrict__ B,
        const float* __restrict__ bias, const float* __restrict__ resid,
        TC* __restrict__ C, int M, int N, int K) {
    __shared__ uint4 As4[1024];          // 128 rows x 8 chunks
    __shared__ uint4 Bs4[TN * 8];        // TN rows x 8 chunks

    const int tid = threadIdx.x;
    const int lane = tid & 63;
    const int wave = tid >> 6;
    const int row16 = lane & 15;
    const int quad = lane >> 4;
    const int n0 = blockIdx.x * TN;
    const int m0 = blockIdx.y * 128;

    constexpr int MI = (TN == 128) ? 4 : 2;           // 16-row frags per wave in M
    const int wy = (TN == 128) ? (wave >> 1) : wave;
    const int wx = (TN == 128) ? (wave & 1) : 0;
    const int m_base = wy * ((TN == 128) ? 64 : 32);
    const int n_base = wx * 64;

    const int rr = lane >> 3;            // 0..7 (row within issue)
    const int kc = (lane & 7) ^ rr;      // swizzled global k-chunk
    const int kx = row16 & 7;            // frag-read deswizzle key

    const bf16_t* AsE = (const bf16_t*)As4;
    const bf16_t* BsE = (const bf16_t*)Bs4;

    f32x4 acc[MI][4] = {};

    for (int k0 = 0; k0 < K; k0 += 64) {
        // stage A: 16 issues x 8 rows
#pragma unroll
        for (int it = 0; it < 4; it++) {
            int issue = it * 4 + wave;
            int r = issue * 8 + rr;
            gld_lds16(A + (size_t)(m0 + r) * K + k0 + kc * 8, &As4[issue * 64]);
        }
        // stage B: TN/8 issues
#pragma unroll
        for (int it = 0; it < TN / 32; it++) {
            int issue = it * 4 + wave;
            int r = issue * 8 + rr;
            gld_lds16(B + (size_t)(n0 + r) * K + k0 + kc * 8, &Bs4[issue * 64]);
        }
        __syncthreads();
#pragma unroll
        for (int s = 0; s < 2; s++) {
            const int kq = s * 4 + quad;
            const int kcs = (kq ^ kx) * 8;
            bf16x8 af[MI], bfr[4];
#pragma unroll
            for (int i = 0; i < MI; i++)
                af[i] = *(const bf16x8*)&AsE[(m_base + i * 16 + row16) * 64 + kcs];
#pragma unroll
            for (int j = 0; j < 4; j++)
                bfr[j] = *(const bf16x8*)&BsE[(n_base + j * 16 + row16) * 64 + kcs];
#pragma unroll
            for (int i = 0; i < MI; i++)
#pragma unroll
                for (int j = 0; j < 4; j++)
                    acc[i][j] = __builtin_amdgcn_mfma_f32_16x16x32_bf16(af[i], bfr[j], acc[i][j], 0, 0, 0);
        }
        __syncthreads();
    }

#pragma unroll
    for (int i = 0; i < MI; i++) {
#pragma unroll
        for (int j = 0; j < 4; j++) {
            int col = n0 + n_base + j * 16 + row16;
            float bsv = bias[col];
#pragma unroll
            for (int r = 0; r < 4; r++) {
                int row = m0 + m_base + i * 16 + quad * 4 + r;
                float val = acc[i][j][r] + bsv;
                if (RESID) val += resid[(size_t)row * N + col];
                if (RELU) val = fmaxf(val, 0.0f);
                size_t caddr = KREMAP
                    ? ((size_t)(row >> 2) * KSTR + (size_t)(row & 3) * 512 + col)
                    : ((size_t)row * N + col);
                stfl(&C[caddr], val);
            }
        }
    }
}

// ---------- transpose: in[(key*4+b)*512 + c] -> out[(b*512+c)*VSTR + key] ----------
__global__ __launch_bounds__(256) void transpose_kv(const bf16_t* __restrict__ kb,
                                                    bf16_t* __restrict__ kT) {
    __shared__ bf16_t tile[64][80];
    const int kt = blockIdx.x * 64;
    const int ct = blockIdx.y * 64;
    const int b  = blockIdx.z;
    const int t = threadIdx.x;
    {
        int kl = t >> 2, cl = (t & 3) * 16;
        const bf16_t* src = kb + ((size_t)(kt + kl) * 4 + b) * 512 + ct + cl;
        *(uint4*)&tile[kl][cl]     = *(const uint4*)src;
        *(uint4*)&tile[kl][cl + 8] = *(const uint4*)(src + 8);
    }
    __syncthreads();
    {
        int cl2 = t >> 2, ks = (t & 3) * 16;
        __attribute__((aligned(16))) bf16_t vals[16];
#pragma unroll
        for (int j = 0; j < 16; j++) vals[j] = tile[ks + j][cl2];
        bf16_t* dst = kT + ((size_t)b * 512 + ct + cl2) * VSTR + kt + ks;
        *(uint4*)dst       = *(const uint4*)&vals[0];
        *(uint4*)(dst + 8) = *(const uint4*)&vals[8];
    }
}

// ======== attn v6 helpers: statically-indexed ping-pong load groups ========
// Rule #20: all buffer indices are compile-time constants (full inner unroll);
// two named buffer sets alternate via manually 2x-unrolled outer loop.
__device__ __forceinline__ void qk_issue(const bf16_t* kb_base, int us, int g,
                                         int row16, bf16x8 (&b0)[8], bf16x8 (&b1)[8]) {
#pragma unroll
    for (int j = 0; j < 8; ++j) {
        int key = us + (g * 8 + j) * 16 + row16;
        int key_eff = key > 4095 ? 4095 : key;
        const bf16_t* kr = kb_base + (size_t)key_eff * KSTR;
        b0[j] = *(const bf16x8*)kr;
        b1[j] = *(const bf16x8*)(kr + 32);
    }
}

__device__ __forceinline__ void qk_compute(int g, bf16x8 (&b0)[8], bf16x8 (&b1)[8],
        const bf16x8 aq0, const bf16x8 aq1, float (&l)[4], bf16_t* PsH,
        int row16, int quad, const int (&sq)[4], const int (&eq)[4], int us) {
#pragma unroll
    for (int j = 0; j < 8; ++j) {
        int it = g * 8 + j;
        f32x4 acc = {};
        acc = __builtin_amdgcn_mfma_f32_16x16x32_bf16(aq0, b0[j], acc, 0, 0, 0);
        acc = __builtin_amdgcn_mfma_f32_16x16x32_bf16(aq1, b1[j], acc, 0, 0, 0);
        int key = us + it * 16 + row16;
#pragma unroll
        for (int r = 0; r < 4; r++) {
            int ql = quad * 4 + r;
            bool valid = (key >= sq[r]) && (key < eq[r]);
            float p = valid ? __expf(0.125f * acc[r]) : 0.0f;
            l[r] += p;
            if (ql < 8) PsH[ql * 904 + it * 16 + row16] = __float2bfloat16(p);
        }
    }
}

__device__ __forceinline__ void pv_issue(const bf16_t* vbase, int g, int row16, int quad,
                                         bf16x8 (&vb)[4][4]) {
#pragma unroll
    for (int j = 0; j < 4; ++j) {
        int it = g * 4 + j;
#pragma unroll
        for (int nt = 0; nt < 4; ++nt)
            vb[j][nt] = *(const bf16x8*)(vbase + (size_t)(nt * 16 + row16) * VSTR
                                         + it * 32 + quad * 8);
    }
}

__device__ __forceinline__ void pv_compute(int g, bf16x8 (&vb)[4][4], const bf16_t* PsH,
        const bf16_t* Zrow, int row16, int quad, f32x4 (&o)[4]) {
#pragma unroll
    for (int j = 0; j < 4; ++j) {
        int it = g * 4 + j;
        const bf16_t* ap_src = (row16 < 8) ? &PsH[row16 * 904 + it * 32 + quad * 8]
                                           : &Zrow[0];
        bf16x8 ap = *(const bf16x8*)ap_src;
#pragma unroll
        for (int nt = 0; nt < 4; ++nt)
            o[nt] = __builtin_amdgcn_mfma_f32_16x16x32_bf16(ap, vb[j][nt], o[nt], 0, 0, 0);
    }
}

// ---------- MFMA flash attention v6: deep register-pipelined loads ----------
// R4 post-mortem: invariant ~700cy per load per wave across R0/R1/R4 ==
// per-wave load-latency serialization (pipeline depth ~1). v6: QK = 7 groups
// of 8 iters, PV = 7 groups of 4, ping-pong named register sets (static
// indexing, no scratch), group g+1's 16 loads in flight during group g's
// compute. QK->PV barrier removed (PV reads only own-head Ps); barrier only
// before the cross-head mean.
__global__ __launch_bounds__(512, 1) void attn_mfma(
        const bf16_t* __restrict__ qb,   // [2048,512] rows (q*4+b)
        const bf16_t* __restrict__ kb,   // [4096][KSTR] key-padded
        const bf16_t* __restrict__ vT,   // [4][512][VSTR]
        bf16_t* __restrict__ ctx,        // [2048,512]
        float* __restrict__ attn_out) {  // [4][512][4096], written in full here
    extern __shared__ char smem[];
    bf16_t* Ps   = (bf16_t*)smem;                         // [8 heads][8 q][904]
    bf16_t* Qs   = (bf16_t*)(smem + 115712);              // [8 q][520]
    bf16_t* Zrow = (bf16_t*)(smem + 115712 + 8320);       // [904]
    float*  Ls   = (float*)(smem + 115712 + 8320 + 1808); // [8 heads][8 q] 1/l

    const int blk = blockIdx.x;
    const int b  = (blk & 7) >> 1;                 // batch locked to XCD pair
    const int qt = ((blk >> 3) << 1) | (blk & 1);  // 0..63
    const int q0 = qt * 8;
    const int tid = threadIdx.x;
    const int lane = tid & 63;
    const int h = tid >> 6;          // wave = head 0..7
    const int hoffg = h * HEADDIM;
    const int row16 = lane & 15;
    const int quad = lane >> 4;

    int us; { int s = q0 * 8, e = s + 827; if (e > 4095) s = 3268; us = s; }
    int sq[4], eq[4];
#pragma unroll
    for (int r = 0; r < 4; r++) {
        int ql = quad * 4 + r;
        if (ql < 8) {
            int s = (q0 + ql) * 8, e = s + 827;
            if (e > 4095) { s = 3268; e = 4096; }
            sq[r] = s; eq[r] = e;
        } else { sq[r] = 0; eq[r] = 0; }
    }

    {   // stage Q: 8 rows x 512 cols (16B per thread)
        int r = tid >> 6, coff = (tid & 63) * 8;
        *(uint4*)&Qs[r * 520 + coff] =
            *(const uint4*)(qb + ((size_t)(q0 + r) * 4 + b) * 512 + coff);
        if (tid < 113) { uint4 z = {0, 0, 0, 0}; *(uint4*)&Zrow[tid * 8] = z; }
    }
    __syncthreads();

    const bf16_t* q0p = (row16 < 8) ? &Qs[row16 * 520 + hoffg + quad * 8] : &Zrow[0];
    const bf16_t* q1p = (row16 < 8) ? &Qs[row16 * 520 + hoffg + 32 + quad * 8] : &Zrow[8];
    const bf16x8 aq0 = *(const bf16x8*)q0p;
    const bf16x8 aq1 = *(const bf16x8*)q1p;

    bf16_t* PsH = Ps + h * 8 * 904;
    const bf16_t* kb_base = kb + b * 512 + hoffg + quad * 8;

    // ---- QK: 7 groups of 8, 2-deep ping-pong register pipeline ----
    bf16x8 ka0[8], ka1[8], kc0[8], kc1[8];
    float l[4] = {0.f, 0.f, 0.f, 0.f};
    qk_issue(kb_base, us, 0, row16, ka0, ka1);
    for (int gg = 0; gg < 3; ++gg) {
        qk_issue(kb_base, us, 2 * gg + 1, row16, kc0, kc1);
        qk_compute(2 * gg, ka0, ka1, aq0, aq1, l, PsH, row16, quad, sq, eq, us);
        qk_issue(kb_base, us, 2 * gg + 2, row16, ka0, ka1);
        qk_compute(2 * gg + 1, kc0, kc1, aq0, aq1, l, PsH, row16, quad, sq, eq, us);
    }
    // PV group-0 loads issue before the final QK compute + the shuffle reduce
    bf16x8 va[4][4], vb_[4][4];
    const bf16_t* vbase = vT + (size_t)(b * 512 + hoffg) * VSTR + us;
    pv_issue(vbase, 0, row16, quad, va);
    qk_compute(6, ka0, ka1, aq0, aq1, l, PsH, row16, quad, sq, eq, us);

#pragma unroll
    for (int off = 1; off < 16; off <<= 1) {
#pragma unroll
        for (int r = 0; r < 4; r++) l[r] += __shfl_xor(l[r], off, 64);
    }
    float linv[4];
#pragma unroll
    for (int r = 0; r < 4; r++) linv[r] = 1.0f / l[r];
    if (row16 == 0) {
#pragma unroll
        for (int r = 0; r < 4; r++) {
            int ql = quad * 4 + r;
            if (ql < 8) Ls[h * 8 + ql] = linv[r];
        }
    }

    // ---- PV: 7 groups of 4, same ping-pong (no barrier: own-head Ps only) ----
    f32x4 o[4] = {};
    for (int gg = 0; gg < 3; ++gg) {
        pv_issue(vbase, 2 * gg + 1, row16, quad, vb_);
        pv_compute(2 * gg, va, PsH, Zrow, row16, quad, o);
        pv_issue(vbase, 2 * gg + 2, row16, quad, va);
        pv_compute(2 * gg + 1, vb_, PsH, Zrow, row16, quad, o);
    }
    pv_compute(6, va, PsH, Zrow, row16, quad, o);

    __syncthreads();   // all heads' Ps + Ls final -> mean may read

    // ---- attn_out head-mean: full-row stores (zeros outside window) ----
    {
        int qq = h;                    // wave qq owns q-row q0+qq entirely
        float ls[8];
#pragma unroll
        for (int hh = 0; hh < 8; ++hh) ls[hh] = 0.125f * Ls[hh * 8 + qq];
        float* rowp = attn_out + ((size_t)b * LQ + q0 + qq) * LK;
        const bf16_t* ps = Ps + qq * 904;
        // 4096 cols = 1024 float4 = 64 lanes x 16 iters
        for (int it = 0; it < 16; ++it) {
            int c4 = (it * 64 + lane) * 4;          // first col of this float4
            float4 v = {0.f, 0.f, 0.f, 0.f};
            int off = c4 - us;                      // Ps col of element 0
            if (off >= -3 && off < 896) {
#pragma unroll
                for (int e = 0; e < 4; ++e) {
                    int pc = off + e;
                    float s = 0.f;
                    if (pc >= 0 && pc < 896) {
#pragma unroll
                        for (int hh = 0; hh < 8; ++hh)
                            s += ls[hh] * tofl(ps[hh * 8 * 904 + pc]);
                    }
                    (&v.x)[e] = s;
                }
            }
            *(float4*)(rowp + c4) = v;
        }
    }

    // ---- ctx write (own head, no cross-wave combine) ----
#pragma unroll
    for (int nt = 0; nt < 4; nt++) {
#pragma unroll
        for (int r = 0; r < 4; r++) {
            int ql = quad * 4 + r;
            if (ql < 8) {
                ctx[((size_t)(q0 + ql) * 4 + b) * 512 + hoffg + nt * 16 + row16] =
                    __float2bfloat16(o[nt][r] * linv[r]);
            }
        }
    }
}

extern "C" void kernel_launch(void* const* d_in, const int* in_sizes, int n_in,
                              void* d_out, int out_size, void* d_ws, size_t ws_size,
                              hipStream_t stream) {
    const float* tgt    = (const float*)d_in[0];
    const float* memory = (const float*)d_in[1];
    const float* Wq = (const float*)d_in[2];
    const float* bq = (const float*)d_in[3];
    const float* Wk = (const float*)d_in[4];
    const float* bk = (const float*)d_in[5];
    const float* Wv = (const float*)d_in[6];
    const float* bv = (const float*)d_in[7];
    const float* Wo = (const float*)d_in[8];
    const float* bo = (const float*)d_in[9];
    const float* W1 = (const float*)d_in[10];
    const float* b1 = (const float*)d_in[11];
    const float* W2 = (const float*)d_in[12];
    const float* b2 = (const float*)d_in[13];
    const float* ln1w = (const float*)d_in[14];
    const float* ln1b = (const float*)d_in[15];
    const float* ln2w = (const float*)d_in[16];
    const float* ln2b = (const float*)d_in[17];
    const float* ln3w = (const float*)d_in[18];
    const float* ln3b = (const float*)d_in[19];
    const float* ln4w = (const float*)d_in[20];
    const float* ln4b = (const float*)d_in[21];

    const size_t M1 = (size_t)LQ * BATCH;      // 2048
    const size_t M2 = (size_t)LK * BATCH;      // 16384
    const size_t SZ1 = M1 * DMODEL;

    // ---- workspace map (64 MiB, lifetime-aliased; padded K/vT) ----
    char* wsb = (char*)d_ws;
    const size_t MB = 1 << 20;
    bf16_t* m_buf   = (bf16_t*)(wsb + 0 * MB);   // [2->5], 16MB
    bf16_t* vT_buf  = (bf16_t*)(wsb + 0 * MB);   // [6->7], 16.13MB (m dead)
    bf16_t* h_buf   = (bf16_t*)(wsb + 0 * MB);   // [10->11], 8MB (vT dead)
    bf16_t* k_buf   = (bf16_t*)(wsb + 17 * MB);  // [4->7], 16.25MB padded
    float*  xres    = (float*)(wsb + 17 * MB);   // [8->9], 4MB (k dead)
    float*  xln_f   = (float*)(wsb + 21 * MB);   // [9->11], 4MB
    float*  x2_buf  = (float*)(wsb + 25 * MB);   // [11->12], 4MB
    bf16_t* W2_bf   = (bf16_t*)(wsb + 34 * MB);  // [6.5->11], 2MB (v region head, v dead)
    bf16_t* v_buf   = (bf16_t*)(wsb + 34 * MB);  // [5->6], 16MB
    bf16_t* t_bf    = (bf16_t*)(wsb + 50 * MB);  // [2->3], 2MB
    bf16_t* xln_bf  = (bf16_t*)(wsb + 50 * MB);  // [9->10], 2MB (t_bf dead)
    float*  t_f32   = (float*)(wsb + 52 * MB);   // [2->8], 4MB
    bf16_t* q_bf    = (bf16_t*)(wsb + 56 * MB);  // [3->7], 2MB
    bf16_t* ctx_buf = (bf16_t*)(wsb + 58 * MB);  // [7->8], 2MB
    bf16_t* wqkvo   = (bf16_t*)(wsb + 60 * MB);  // [1->8], 2MB
    bf16_t* W1_bf   = (bf16_t*)(wsb + 62 * MB);  // [1->10], 2MB

    bf16_t* Wq_bf = wqkvo;
    bf16_t* Wk_bf = wqkvo + 262144;
    bf16_t* Wv_bf = wqkvo + 2 * 262144;
    bf16_t* Wo_bf = wqkvo + 3 * 262144;

    float* out_x    = (float*)d_out;
    float* out_attn = out_x + SZ1;

    // 1. qkvo + W1 conversions (attn_out fully written by attn itself)
    prep_kernel<<<dim3(2048), dim3(256), 0, stream>>>(
        Wq, Wk, Wv, Wo, W1, wqkvo, W1_bf);

    // 2. LN1 (dual) + LN2 fused
    ln12_kernel<<<dim3(M1 + M2), dim3(256), 0, stream>>>(
        tgt, memory, ln1w, ln1b, ln2w, ln2b, t_bf, t_f32, m_buf);

    // 3-5. projections (K-proj writes padded k_buf layout)
    gemm_mfma<64, bf16_t, false, false><<<dim3(8, 16), dim3(256), 0, stream>>>(
        t_bf, Wq_bf, bq, nullptr, q_bf, M1, DMODEL, DMODEL);
    gemm_mfma<128, bf16_t, false, false, true><<<dim3(4, 128), dim3(256), 0, stream>>>(
        m_buf, Wk_bf, bk, nullptr, k_buf, M2, DMODEL, DMODEL);
    gemm_mfma<128, bf16_t, false, false><<<dim3(4, 128), dim3(256), 0, stream>>>(
        m_buf, Wv_bf, bv, nullptr, v_buf, M2, DMODEL, DMODEL);

    // 6. V transpose to padded [b][d][VSTR] (m_buf dead -> vT region)
    transpose_kv<<<dim3(64, 8, 4), dim3(256), 0, stream>>>(v_buf, vT_buf);

    // 6.5 W2 conversion into dead v_buf head
    conv_w2<<<dim3(1024), dim3(256), 0, stream>>>(W2, W2_bf);

    // 7. attention: 256 blocks x 8 waves (= 8 heads), 126KB dynamic LDS
    const int attn_lds = 115712 + 8320 + 1808 + 256;   // 126096 B
    hipFuncSetAttribute((const void*)attn_mfma,
                        hipFuncAttributeMaxDynamicSharedMemorySize, attn_lds);
    attn_mfma<<<dim3(256), dim3(512), attn_lds, stream>>>(
        q_bf, k_buf, vT_buf, ctx_buf, out_attn);

    // 8. out proj + residual(t) -> xres (k_buf region, dead)
    gemm_mfma<64, float, false, true><<<dim3(8, 16), dim3(256), 0, stream>>>(
        ctx_buf, Wo_bf, bo, t_f32, xres, M1, DMODEL, DMODEL);

    // 9. LN3 (dual)
    ln_kernel<bf16_t, true><<<dim3(M1), dim3(256), 0, stream>>>(xres, ln3w, ln3b, xln_bf, xln_f);

    // 10. FF1 (relu)
    gemm_mfma<128, bf16_t, true, false><<<dim3(16, 16), dim3(256), 0, stream>>>(
        xln_bf, W1_bf, b1, nullptr, h_buf, M1, DFF, DMODEL);

    // 11. FF2 + residual(xln)
    gemm_mfma<64, float, false, true><<<dim3(8, 16), dim3(256), 0, stream>>>(
        h_buf, W2_bf, b2, xln_f, x2_buf, M1, DMODEL, DFF);

    // 12. LN4 -> fp32 out
    ln_kernel<float, false><<<dim3(M1), dim3(256), 0, stream>>>(x2_buf, ln4w, ln4b, out_x, nullptr);
}